// Round 12
// baseline (181.067 us; speedup 1.0000x reference)
//
#include <hip/hip_runtime.h>

#define B_ 4
#define C_ 256
#define T_ 2304
#define HD 32
#define GSZ (32 * T_)                 // elems per groupnorm group = 73728
#define SCL2E (0.17677669529663687f * 1.44269504088896f)  // (1/sqrt(32)) * log2(e)

typedef short bf16x8 __attribute__((ext_vector_type(8)));
typedef float f32x4 __attribute__((ext_vector_type(4)));
typedef unsigned int u32x2 __attribute__((ext_vector_type(2)));

__device__ inline unsigned short f2bf(float f) {
  unsigned int u = __float_as_uint(f);
  return (unsigned short)((u + 0x7FFFu + ((u >> 16) & 1u)) >> 16);
}

__device__ inline float fexp2(float x) {
  float r;
  asm("v_exp_f32 %0, %1" : "=v"(r) : "v"(x));
  return r;
}

__device__ inline unsigned cvtpk(float lo, float hi) {
  unsigned r;
  asm("v_cvt_pk_bf16_f32 %0, %1, %2" : "=v"(r) : "v"(lo), "v"(hi));
  return r;
}

// ---------------- weights -> bf16  +  groupnorm partial stats (merged) ----------------
__global__ void prep(const float* wq, const float* wp, const float* x,
                     unsigned short* oq, unsigned short* op, float* ws1) {
  if (blockIdx.x < 1024) {
    int i = blockIdx.x * 256 + threadIdx.x;
    const int n1 = 3 * C_ * C_;
    if (i < n1) oq[i] = f2bf(wq[i]);
    else        op[i - n1] = f2bf(wp[i - n1]);
    return;
  }
  int bid = blockIdx.x - 1024;
  int bg = bid >> 3, sl = bid & 7;
  const float4* p = (const float4*)(x + (size_t)bg * GSZ + sl * (GSZ / 8));
  float s = 0.f, q = 0.f;
  for (int it = 0; it < 9; ++it) {
    float4 v = p[it * 256 + threadIdx.x];
    s += v.x + v.y + v.z + v.w;
    q += v.x * v.x + v.y * v.y + v.z * v.z + v.w * v.w;
  }
  for (int off = 32; off; off >>= 1) {
    s += __shfl_down(s, off);
    q += __shfl_down(q, off);
  }
  __shared__ float red[8];
  int w = threadIdx.x >> 6;
  if ((threadIdx.x & 63) == 0) { red[w * 2] = s; red[w * 2 + 1] = q; }
  __syncthreads();
  if (threadIdx.x == 0) {
    float S = red[0] + red[2] + red[4] + red[6];
    float Q = red[1] + red[3] + red[5] + red[7];
    ws1[bid * 2] = S;
    ws1[bid * 2 + 1] = Q;
  }
}

// ---------------- groupnorm: finalize stats (inline) + normalize + transpose to nT[B][T][C] --
__global__ void gn_norm(const float* x, const float* ws1, const float* gamma,
                        const float* beta, unsigned short* nT) {
  int b = blockIdx.y, t0 = blockIdx.x * 32;
  __shared__ unsigned short tile[32 * 264];
  __shared__ float stl[16];
  int tid = threadIdx.x;
  if (tid < 8) {
    float S = 0.f, Q = 0.f;
    for (int sl = 0; sl < 8; ++sl) {
      S += ws1[((b * 8 + tid) * 8 + sl) * 2];
      Q += ws1[((b * 8 + tid) * 8 + sl) * 2 + 1];
    }
    float mean = S / (float)GSZ;
    float var = Q / (float)GSZ - mean * mean;
    stl[tid * 2] = mean;
    stl[tid * 2 + 1] = rsqrtf(var + 1e-5f);
  }
  __syncthreads();
#pragma unroll
  for (int it = 0; it < 8; ++it) {
    int qd = it * 256 + tid;
    int c = qd >> 3, tq = qd & 7;
    float4 v = *(const float4*)&x[((size_t)b * C_ + c) * T_ + t0 + tq * 4];
    int g = c >> 5;
    float mean = stl[g * 2], rstd = stl[g * 2 + 1];
    float sc = rstd * gamma[c];
    float sh = beta[c] - mean * sc;
    tile[(tq * 4 + 0) * 264 + c] = f2bf(v.x * sc + sh);
    tile[(tq * 4 + 1) * 264 + c] = f2bf(v.y * sc + sh);
    tile[(tq * 4 + 2) * 264 + c] = f2bf(v.z * sc + sh);
    tile[(tq * 4 + 3) * 264 + c] = f2bf(v.w * sc + sh);
  }
  __syncthreads();
#pragma unroll
  for (int it = 0; it < 4; ++it) {
    int qd = it * 256 + tid;
    int tt = qd >> 5, c8 = (qd & 31) * 8;
    *(uint4*)&nT[((size_t)b * T_ + t0 + tt) * C_ + c8] = *(const uint4*)&tile[tt * 264 + c8];
  }
}

// ---------------- QKV GEMM: [768,256] x nT -> qT/kT [b,h,t,d], v [b,h,d,t] ----------------
// Coalesced epilogue: acc -> LDS transpose tile -> 16B stores. Each block handles one of
// q/k/v exclusively (blockIdx.y: 0-3=q, 4-7=k, 8-11=v). q pre-scaled by SCL2E.
__global__ __launch_bounds__(256) void qkv_gemm(const unsigned short* W, const unsigned short* nT,
                                                const float* bias, unsigned short* qT,
                                                unsigned short* kT, unsigned short* vW) {
  __shared__ unsigned short tt[64][72];
  int b = blockIdx.z;
  int lane = threadIdx.x & 63, w = threadIdx.x >> 6;
  int r16 = lane & 15, g4 = lane >> 4;
  int y = blockIdx.y;
  int type = y >> 2;                    // 0=q 1=k 2=v
  int m0 = y * 64 + (w >> 1) * 32;
  int n0 = blockIdx.x * 64 + (w & 1) * 32;
  const bf16x8* Wv = (const bf16x8*)W;
  const bf16x8* Nv = (const bf16x8*)(nT + (size_t)b * T_ * C_);
  f32x4 acc[2][2] = {};
  for (int k0 = 0; k0 < C_; k0 += 32) {
    bf16x8 af[2], bfr[2];
    for (int mi = 0; mi < 2; ++mi)
      af[mi] = Wv[((m0 + mi * 16 + r16) * C_ + k0 + g4 * 8) >> 3];
    for (int ni = 0; ni < 2; ++ni)
      bfr[ni] = Nv[((n0 + ni * 16 + r16) * C_ + k0 + g4 * 8) >> 3];
    for (int mi = 0; mi < 2; ++mi)
      for (int ni = 0; ni < 2; ++ni)
        acc[mi][ni] = __builtin_amdgcn_mfma_f32_16x16x32_bf16(af[mi], bfr[ni], acc[mi][ni], 0, 0, 0);
  }
#pragma unroll
  for (int mi = 0; mi < 2; ++mi) {
#pragma unroll
    for (int ni = 0; ni < 2; ++ni) {
      int t_loc = (w & 1) * 32 + ni * 16 + r16;
      int o_loc = (w >> 1) * 32 + mi * 16 + g4 * 4;
      int o = y * 64 + o_loc;
      float v0 = acc[mi][ni][0] + bias[o + 0];
      float v1 = acc[mi][ni][1] + bias[o + 1];
      float v2 = acc[mi][ni][2] + bias[o + 2];
      float v3 = acc[mi][ni][3] + bias[o + 3];
      if (type == 0) { v0 *= SCL2E; v1 *= SCL2E; v2 *= SCL2E; v3 *= SCL2E; }
      if (type < 2) {
        u32x2 pw = {cvtpk(v0, v1), cvtpk(v2, v3)};
        *(u32x2*)&tt[t_loc][o_loc] = pw;          // [t][o]
      } else {
        tt[o_loc + 0][t_loc] = f2bf(v0);          // [o][t]
        tt[o_loc + 1][t_loc] = f2bf(v1);
        tt[o_loc + 2][t_loc] = f2bf(v2);
        tt[o_loc + 3][t_loc] = f2bf(v3);
      }
    }
  }
  __syncthreads();
  int tid = threadIdx.x;
  if (type < 2) {
    unsigned short* dst = (type == 0) ? qT : kT;
    int obase = y * 64 - type * 256;
    int t_loc = tid >> 2;
    int tg = blockIdx.x * 64 + t_loc;
#pragma unroll
    for (int half = 0; half < 2; ++half) {
      int o_loc = half * 32 + (tid & 3) * 8;
      int o2 = obase + o_loc;
      int hh = o2 >> 5, d = o2 & 31;
      *(uint4*)&dst[(((size_t)b * 8 + hh) * T_ + tg) * HD + d] = *(const uint4*)&tt[t_loc][o_loc];
    }
  } else {
    int obase = y * 64 - 512;
    int o_loc = tid >> 2;
    int o2 = obase + o_loc;
    int hh = o2 >> 5, d = o2 & 31;
    unsigned short* vdst = vW + ((size_t)(b * 8 + hh) * HD + d) * T_ + blockIdx.x * 64;
#pragma unroll
    for (int half = 0; half < 2; ++half) {
      int t_loc = half * 32 + (tid & 3) * 8;
      *(uint4*)&vdst[t_loc] = *(const uint4*)&tt[o_loc][t_loc];
    }
  }
}

// ---------------- flash attention: no LDS/barriers; reg-dbuf L2 fragments; XCD-local bh ----
// 1 wave x 32 q-rows per block. Math identical to R8/R10/R11 (kappa-paired register PV).
// Bijective XCD swizzle: consecutive-XCD blocks get contiguous bh range -> per-XCD L2
// working set = 4 bh x 294 KB = 1.2 MB (fits 4 MiB).
__global__ __launch_bounds__(64) void attn(const unsigned short* qT, const unsigned short* kT,
                                           const unsigned short* vW, unsigned short* attnT) {
  int wg = blockIdx.x;
  int swz = (wg & 7) * 288 + (wg >> 3);   // bijective on [0,2304)
  int bh = swz / 72, qt = swz % 72;       // qt: 32 q-rows each
  int lane = threadIdx.x;
  int r16 = lane & 15, g4 = lane >> 4;
  const unsigned short* qB = qT + (size_t)bh * T_ * HD;
  const unsigned short* kB = kT + (size_t)bh * T_ * HD;
  const unsigned short* vB = vW + (size_t)bh * HD * T_;
  int qbase = qt * 32;
  bf16x8 qfA = *(const bf16x8*)(qB + (qbase + r16) * HD + g4 * 8);
  bf16x8 qfB = *(const bf16x8*)(qB + (qbase + 16 + r16) * HD + g4 * 8);
  float lA = 0.f, lB = 0.f;
  f32x4 accA0 = {}, accA1 = {}, accB0 = {}, accB1 = {};

  // per-lane base pointers
  const unsigned short* kP  = kB + (size_t)r16 * HD + g4 * 8;        // + s*HD walks s
  const unsigned short* vP0 = vB + (size_t)r16 * T_ + 4 * g4;        // d row r16
  const unsigned short* vP1 = vB + (size_t)(16 + r16) * T_ + 4 * g4; // d row 16+r16

  union PU { unsigned u[4]; bf16x8 v; };
  union VU { int2 d2[2]; bf16x8 v; };

  // two static fragment sets (no dynamic indexing - stays in registers)
  bf16x8 kf0A, kf1A, kf2A, kf3A, kf0B, kf1B, kf2B, kf3B;
  VU vf00A, vf01A, vf10A, vf11A, vf00B, vf01B, vf10B, vf11B;

#define LOADF(sfx, t_) {                                                          \
    int s0g = (t_) * 64;                                                          \
    kf0##sfx = *(const bf16x8*)(kP + (size_t)(s0g) * HD);                         \
    kf1##sfx = *(const bf16x8*)(kP + (size_t)(s0g + 16) * HD);                    \
    kf2##sfx = *(const bf16x8*)(kP + (size_t)(s0g + 32) * HD);                    \
    kf3##sfx = *(const bf16x8*)(kP + (size_t)(s0g + 48) * HD);                    \
    vf00##sfx.d2[0] = *(const int2*)(vP0 + s0g);                                  \
    vf00##sfx.d2[1] = *(const int2*)(vP0 + s0g + 16);                             \
    vf01##sfx.d2[0] = *(const int2*)(vP1 + s0g);                                  \
    vf01##sfx.d2[1] = *(const int2*)(vP1 + s0g + 16);                             \
    vf10##sfx.d2[0] = *(const int2*)(vP0 + s0g + 32);                             \
    vf10##sfx.d2[1] = *(const int2*)(vP0 + s0g + 48);                             \
    vf11##sfx.d2[0] = *(const int2*)(vP1 + s0g + 32);                             \
    vf11##sfx.d2[1] = *(const int2*)(vP1 + s0g + 48);                             \
  }

// QK -> exp -> pack (lane-local) -> PV through registers. kappa(g4,j) = 4g4+(j&3)+16(j>>2).
#define SUBTILE(qf, lsum, acc0, acc1, kf0, kf1, kf2, kf3, vf00, vf01, vf10, vf11) { \
    f32x4 z = {};                                                                 \
    f32x4 s0 = __builtin_amdgcn_mfma_f32_16x16x32_bf16(kf0, qf, z, 0, 0, 0);      \
    f32x4 s1 = __builtin_amdgcn_mfma_f32_16x16x32_bf16(kf1, qf, z, 0, 0, 0);      \
    f32x4 s2 = __builtin_amdgcn_mfma_f32_16x16x32_bf16(kf2, qf, z, 0, 0, 0);      \
    f32x4 s3 = __builtin_amdgcn_mfma_f32_16x16x32_bf16(kf3, qf, z, 0, 0, 0);      \
    float p0 = fexp2(s0[0]), p1 = fexp2(s0[1]), p2 = fexp2(s0[2]), p3 = fexp2(s0[3]); \
    float p4 = fexp2(s1[0]), p5 = fexp2(s1[1]), p6 = fexp2(s1[2]), p7 = fexp2(s1[3]); \
    float p8 = fexp2(s2[0]), p9 = fexp2(s2[1]), pa = fexp2(s2[2]), pb = fexp2(s2[3]); \
    float pc = fexp2(s3[0]), pd = fexp2(s3[1]), pe = fexp2(s3[2]), pf = fexp2(s3[3]); \
    float ps = ((p0 + p1) + (p2 + p3)) + ((p4 + p5) + (p6 + p7)) +                \
               ((p8 + p9) + (pa + pb)) + ((pc + pd) + (pe + pf));                 \
    PU w0, w1;                                                                    \
    w0.u[0] = cvtpk(p0, p1); w0.u[1] = cvtpk(p2, p3);                             \
    w0.u[2] = cvtpk(p4, p5); w0.u[3] = cvtpk(p6, p7);                             \
    w1.u[0] = cvtpk(p8, p9); w1.u[1] = cvtpk(pa, pb);                             \
    w1.u[2] = cvtpk(pc, pd); w1.u[3] = cvtpk(pe, pf);                             \
    ps += __shfl_xor(ps, 16);                                                     \
    ps += __shfl_xor(ps, 32);                                                     \
    lsum += ps;                                                                   \
    acc0 = __builtin_amdgcn_mfma_f32_16x16x32_bf16(vf00.v, w0.v, acc0, 0, 0, 0);  \
    acc1 = __builtin_amdgcn_mfma_f32_16x16x32_bf16(vf01.v, w0.v, acc1, 0, 0, 0);  \
    acc0 = __builtin_amdgcn_mfma_f32_16x16x32_bf16(vf10.v, w1.v, acc0, 0, 0, 0);  \
    acc1 = __builtin_amdgcn_mfma_f32_16x16x32_bf16(vf11.v, w1.v, acc1, 0, 0, 0);  \
  }

#define CPAIR(sfx)                                                                \
    SUBTILE(qfA, lA, accA0, accA1, kf0##sfx, kf1##sfx, kf2##sfx, kf3##sfx,        \
            vf00##sfx, vf01##sfx, vf10##sfx, vf11##sfx)                           \
    SUBTILE(qfB, lB, accB0, accB1, kf0##sfx, kf1##sfx, kf2##sfx, kf3##sfx,        \
            vf00##sfx, vf01##sfx, vf10##sfx, vf11##sfx)

  LOADF(A, 0)
  for (int t = 0; t < 34; t += 2) {     // steady state: no interior branch
    LOADF(B, t + 1)                     // in flight during compute of A
    CPAIR(A)
    LOADF(A, t + 2)                     // in flight during compute of B
    CPAIR(B)
  }
  LOADF(B, 35)
  CPAIR(A)
  CPAIR(B)

  // output: O[d][q] with q = r16 (lane-local l sums), d = dh*16 + 4g4 + r
  float invA = 1.f / lA;
  float invB = 1.f / lB;
  int b = bh >> 3, h = bh & 7;
  unsigned short* oA = attnT + ((size_t)b * T_ + qbase + r16) * C_ + h * HD + 4 * g4;
  unsigned short* oB = attnT + ((size_t)b * T_ + qbase + 16 + r16) * C_ + h * HD + 4 * g4;
  {
    u32x2 wA0 = {cvtpk(accA0[0] * invA, accA0[1] * invA), cvtpk(accA0[2] * invA, accA0[3] * invA)};
    u32x2 wA1 = {cvtpk(accA1[0] * invA, accA1[1] * invA), cvtpk(accA1[2] * invA, accA1[3] * invA)};
    u32x2 wB0 = {cvtpk(accB0[0] * invB, accB0[1] * invB), cvtpk(accB0[2] * invB, accB0[3] * invB)};
    u32x2 wB1 = {cvtpk(accB1[0] * invB, accB1[1] * invB), cvtpk(accB1[2] * invB, accB1[3] * invB)};
    *(u32x2*)oA = wA0;
    *(u32x2*)(oA + 16) = wA1;
    *(u32x2*)oB = wB0;
    *(u32x2*)(oB + 16) = wB1;
  }
#undef LOADF
#undef SUBTILE
#undef CPAIR
}

// ---------------- proj GEMM + bias + residual ----------------
__global__ __launch_bounds__(256) void proj_gemm(const unsigned short* W, const unsigned short* aT,
                                                 const float* bias, const float* x, float* out) {
  int b = blockIdx.z;
  int lane = threadIdx.x & 63, w = threadIdx.x >> 6;
  int r16 = lane & 15, g4 = lane >> 4;
  int m0 = blockIdx.y * 64 + (w >> 1) * 32;
  int n0 = blockIdx.x * 64 + (w & 1) * 32;
  const bf16x8* Wv = (const bf16x8*)W;
  const bf16x8* Av = (const bf16x8*)(aT + (size_t)b * T_ * C_);
  f32x4 acc[2][2] = {};
  for (int k0 = 0; k0 < C_; k0 += 32) {
    bf16x8 af[2], bfr[2];
    for (int mi = 0; mi < 2; ++mi)
      af[mi] = Wv[((m0 + mi * 16 + r16) * C_ + k0 + g4 * 8) >> 3];
    for (int ni = 0; ni < 2; ++ni)
      bfr[ni] = Av[((n0 + ni * 16 + r16) * C_ + k0 + g4 * 8) >> 3];
    for (int mi = 0; mi < 2; ++mi)
      for (int ni = 0; ni < 2; ++ni)
        acc[mi][ni] = __builtin_amdgcn_mfma_f32_16x16x32_bf16(af[mi], bfr[ni], acc[mi][ni], 0, 0, 0);
  }
  for (int mi = 0; mi < 2; ++mi)
    for (int ni = 0; ni < 2; ++ni) {
      int t = n0 + ni * 16 + r16;
      for (int r = 0; r < 4; ++r) {
        int o = m0 + mi * 16 + g4 * 4 + r;
        size_t idx = ((size_t)b * C_ + o) * T_ + t;
        out[idx] = x[idx] + acc[mi][ni][r] + bias[o];
      }
    }
}

extern "C" void kernel_launch(void* const* d_in, const int* in_sizes, int n_in,
                              void* d_out, int out_size, void* d_ws, size_t ws_size,
                              hipStream_t stream) {
  const float* x  = (const float*)d_in[0];
  const float* gw = (const float*)d_in[1];
  const float* gb = (const float*)d_in[2];
  const float* wq = (const float*)d_in[3];
  const float* bq = (const float*)d_in[4];
  const float* wp = (const float*)d_in[5];
  const float* bp = (const float*)d_in[6];

  char* ws = (char*)d_ws;
  float* ws1 = (float*)ws;                       // 256*2 f32
  unsigned short* wqb = (unsigned short*)(ws + 4096);
  unsigned short* wpb = wqb + 3 * C_ * C_;
  unsigned short* nT  = wpb + C_ * C_;
  const size_t NE = (size_t)B_ * T_ * C_;        // 2359296
  unsigned short* qT = nT + NE;
  unsigned short* kT = qT + NE;
  unsigned short* vW = kT + NE;
  unsigned short* aT = vW + NE;

  prep<<<1280, 256, 0, stream>>>(wq, wp, x, wqb, wpb, ws1);
  gn_norm<<<dim3(72, 4), 256, 0, stream>>>(x, ws1, gw, gb, nT);
  qkv_gemm<<<dim3(36, 12, 4), 256, 0, stream>>>(wqb, nT, bq, qT, kT, vW);
  attn<<<2304, 64, 0, stream>>>(qT, kT, vW, aT);
  proj_gemm<<<dim3(36, 4, 4), 256, 0, stream>>>(wpb, aT, bp, x, (float*)d_out);
}

// Round 13
// 118.852 us; speedup vs baseline: 1.5235x; 1.5235x over previous
//
#include <hip/hip_runtime.h>

#define B_ 4
#define C_ 256
#define T_ 2304
#define HD 32
#define GSZ (32 * T_)                 // elems per groupnorm group = 73728
#define SCL2E (0.17677669529663687f * 1.44269504088896f)  // (1/sqrt(32)) * log2(e)

typedef short bf16x8 __attribute__((ext_vector_type(8)));
typedef float f32x4 __attribute__((ext_vector_type(4)));
typedef unsigned int u32x2 __attribute__((ext_vector_type(2)));

__device__ inline unsigned short f2bf(float f) {
  unsigned int u = __float_as_uint(f);
  return (unsigned short)((u + 0x7FFFu + ((u >> 16) & 1u)) >> 16);
}

__device__ inline float fexp2(float x) {
  float r;
  asm("v_exp_f32 %0, %1" : "=v"(r) : "v"(x));
  return r;
}

__device__ inline unsigned cvtpk(float lo, float hi) {
  unsigned r;
  asm("v_cvt_pk_bf16_f32 %0, %1, %2" : "=v"(r) : "v"(lo), "v"(hi));
  return r;
}

// ---------------- weights -> bf16  +  groupnorm partial stats (merged) ----------------
__global__ void prep(const float* wq, const float* wp, const float* x,
                     unsigned short* oq, unsigned short* op, float* ws1) {
  if (blockIdx.x < 1024) {
    int i = blockIdx.x * 256 + threadIdx.x;
    const int n1 = 3 * C_ * C_;
    if (i < n1) oq[i] = f2bf(wq[i]);
    else        op[i - n1] = f2bf(wp[i - n1]);
    return;
  }
  int bid = blockIdx.x - 1024;
  int bg = bid >> 3, sl = bid & 7;
  const float4* p = (const float4*)(x + (size_t)bg * GSZ + sl * (GSZ / 8));
  float s = 0.f, q = 0.f;
  for (int it = 0; it < 9; ++it) {
    float4 v = p[it * 256 + threadIdx.x];
    s += v.x + v.y + v.z + v.w;
    q += v.x * v.x + v.y * v.y + v.z * v.z + v.w * v.w;
  }
  for (int off = 32; off; off >>= 1) {
    s += __shfl_down(s, off);
    q += __shfl_down(q, off);
  }
  __shared__ float red[8];
  int w = threadIdx.x >> 6;
  if ((threadIdx.x & 63) == 0) { red[w * 2] = s; red[w * 2 + 1] = q; }
  __syncthreads();
  if (threadIdx.x == 0) {
    float S = red[0] + red[2] + red[4] + red[6];
    float Q = red[1] + red[3] + red[5] + red[7];
    ws1[bid * 2] = S;
    ws1[bid * 2 + 1] = Q;
  }
}

// ---------------- groupnorm: finalize stats (inline) + normalize + transpose to nT[B][T][C] --
__global__ void gn_norm(const float* x, const float* ws1, const float* gamma,
                        const float* beta, unsigned short* nT) {
  int b = blockIdx.y, t0 = blockIdx.x * 32;
  __shared__ unsigned short tile[32 * 264];
  __shared__ float stl[16];
  int tid = threadIdx.x;
  if (tid < 8) {
    float S = 0.f, Q = 0.f;
    for (int sl = 0; sl < 8; ++sl) {
      S += ws1[((b * 8 + tid) * 8 + sl) * 2];
      Q += ws1[((b * 8 + tid) * 8 + sl) * 2 + 1];
    }
    float mean = S / (float)GSZ;
    float var = Q / (float)GSZ - mean * mean;
    stl[tid * 2] = mean;
    stl[tid * 2 + 1] = rsqrtf(var + 1e-5f);
  }
  __syncthreads();
#pragma unroll
  for (int it = 0; it < 8; ++it) {
    int qd = it * 256 + tid;
    int c = qd >> 3, tq = qd & 7;
    float4 v = *(const float4*)&x[((size_t)b * C_ + c) * T_ + t0 + tq * 4];
    int g = c >> 5;
    float mean = stl[g * 2], rstd = stl[g * 2 + 1];
    float sc = rstd * gamma[c];
    float sh = beta[c] - mean * sc;
    tile[(tq * 4 + 0) * 264 + c] = f2bf(v.x * sc + sh);
    tile[(tq * 4 + 1) * 264 + c] = f2bf(v.y * sc + sh);
    tile[(tq * 4 + 2) * 264 + c] = f2bf(v.z * sc + sh);
    tile[(tq * 4 + 3) * 264 + c] = f2bf(v.w * sc + sh);
  }
  __syncthreads();
#pragma unroll
  for (int it = 0; it < 4; ++it) {
    int qd = it * 256 + tid;
    int tt = qd >> 5, c8 = (qd & 31) * 8;
    *(uint4*)&nT[((size_t)b * T_ + t0 + tt) * C_ + c8] = *(const uint4*)&tile[tt * 264 + c8];
  }
}

// ---------------- QKV GEMM: [768,256] x nT -> qT/kT [b,h,t,d], v [b,h,d,t] ----------------
// Coalesced epilogue: acc -> LDS transpose tile -> 16B stores. Each block handles one of
// q/k/v exclusively (blockIdx.y: 0-3=q, 4-7=k, 8-11=v). q pre-scaled by SCL2E.
__global__ __launch_bounds__(256) void qkv_gemm(const unsigned short* W, const unsigned short* nT,
                                                const float* bias, unsigned short* qT,
                                                unsigned short* kT, unsigned short* vW) {
  __shared__ unsigned short tt[64][72];
  int b = blockIdx.z;
  int lane = threadIdx.x & 63, w = threadIdx.x >> 6;
  int r16 = lane & 15, g4 = lane >> 4;
  int y = blockIdx.y;
  int type = y >> 2;                    // 0=q 1=k 2=v
  int m0 = y * 64 + (w >> 1) * 32;
  int n0 = blockIdx.x * 64 + (w & 1) * 32;
  const bf16x8* Wv = (const bf16x8*)W;
  const bf16x8* Nv = (const bf16x8*)(nT + (size_t)b * T_ * C_);
  f32x4 acc[2][2] = {};
  for (int k0 = 0; k0 < C_; k0 += 32) {
    bf16x8 af[2], bfr[2];
    for (int mi = 0; mi < 2; ++mi)
      af[mi] = Wv[((m0 + mi * 16 + r16) * C_ + k0 + g4 * 8) >> 3];
    for (int ni = 0; ni < 2; ++ni)
      bfr[ni] = Nv[((n0 + ni * 16 + r16) * C_ + k0 + g4 * 8) >> 3];
    for (int mi = 0; mi < 2; ++mi)
      for (int ni = 0; ni < 2; ++ni)
        acc[mi][ni] = __builtin_amdgcn_mfma_f32_16x16x32_bf16(af[mi], bfr[ni], acc[mi][ni], 0, 0, 0);
  }
#pragma unroll
  for (int mi = 0; mi < 2; ++mi) {
#pragma unroll
    for (int ni = 0; ni < 2; ++ni) {
      int t_loc = (w & 1) * 32 + ni * 16 + r16;
      int o_loc = (w >> 1) * 32 + mi * 16 + g4 * 4;
      int o = y * 64 + o_loc;
      float v0 = acc[mi][ni][0] + bias[o + 0];
      float v1 = acc[mi][ni][1] + bias[o + 1];
      float v2 = acc[mi][ni][2] + bias[o + 2];
      float v3 = acc[mi][ni][3] + bias[o + 3];
      if (type == 0) { v0 *= SCL2E; v1 *= SCL2E; v2 *= SCL2E; v3 *= SCL2E; }
      if (type < 2) {
        u32x2 pw = {cvtpk(v0, v1), cvtpk(v2, v3)};
        *(u32x2*)&tt[t_loc][o_loc] = pw;          // [t][o]
      } else {
        tt[o_loc + 0][t_loc] = f2bf(v0);          // [o][t]
        tt[o_loc + 1][t_loc] = f2bf(v1);
        tt[o_loc + 2][t_loc] = f2bf(v2);
        tt[o_loc + 3][t_loc] = f2bf(v3);
      }
    }
  }
  __syncthreads();
  int tid = threadIdx.x;
  if (type < 2) {
    unsigned short* dst = (type == 0) ? qT : kT;
    int obase = y * 64 - type * 256;
    int t_loc = tid >> 2;
    int tg = blockIdx.x * 64 + t_loc;
#pragma unroll
    for (int half = 0; half < 2; ++half) {
      int o_loc = half * 32 + (tid & 3) * 8;
      int o2 = obase + o_loc;
      int hh = o2 >> 5, d = o2 & 31;
      *(uint4*)&dst[(((size_t)b * 8 + hh) * T_ + tg) * HD + d] = *(const uint4*)&tt[t_loc][o_loc];
    }
  } else {
    int obase = y * 64 - 512;
    int o_loc = tid >> 2;
    int o2 = obase + o_loc;
    int hh = o2 >> 5, d = o2 & 31;
    unsigned short* vdst = vW + ((size_t)(b * 8 + hh) * HD + d) * T_ + blockIdx.x * 64;
#pragma unroll
    for (int half = 0; half < 2; ++half) {
      int t_loc = half * 32 + (tid & 3) * 8;
      *(uint4*)&vdst[t_loc] = *(const uint4*)&tt[o_loc][t_loc];
    }
  }
}

// ---------------- flash attention: 1 wave/block, private LDS tile, ZERO barriers ----------
// Same math as R8 (kappa-paired register PV). Single wave owns its K/V tile: in-order DS
// pipeline makes read(t) -> write(t+1) WAR-safe without __syncthreads; global loads for
// tile t+1 sit in 8 int4 staging regs (compiler-held prefetch, proven in R8).
__global__ __launch_bounds__(64) void attn(const unsigned short* qT, const unsigned short* kT,
                                           const unsigned short* vW, unsigned short* attnT) {
  int b = blockIdx.z, h = blockIdx.y, qt = blockIdx.x;   // qt 0..71, 32 q-rows each
  int lane = threadIdx.x;
  int r16 = lane & 15, g4 = lane >> 4;
  __shared__ short Ks[64 * 40];     // [s][d] padded to 40
  __shared__ short Vs[32 * 72];     // [d][s] padded to 72
  int bh = b * 8 + h;
  const unsigned short* qB = qT + (size_t)bh * T_ * HD;
  const unsigned short* kB = kT + (size_t)bh * T_ * HD;
  const unsigned short* vB = vW + (size_t)bh * HD * T_;
  int qbase = qt * 32;
  bf16x8 qfA = *(const bf16x8*)(qB + (qbase + r16) * HD + g4 * 8);
  bf16x8 qfB = *(const bf16x8*)(qB + (qbase + 16 + r16) * HD + g4 * 8);
  float lA = 0.f, lB = 0.f;
  f32x4 accA0 = {}, accA1 = {}, accB0 = {}, accB1 = {};

  // staging geometry: 64 threads stage the full 8KB tile (8 b128 loads + stores each)
  int krow = lane >> 2, kcol = (lane & 3) * 8;   // K rows krow, +16, +32, +48
  int vrow = lane >> 3, vcol = (lane & 7) * 8;   // V rows vrow, +8, +16, +24
  const unsigned short* kSrc = kB + (size_t)krow * HD + kcol;
  short* kD = &Ks[krow * 40 + kcol];
  const unsigned short* vSrc = vB + (size_t)vrow * T_ + vcol;
  short* vD = &Vs[vrow * 72 + vcol];
  int4 rgK0, rgK1, rgK2, rgK3, rgV0, rgV1, rgV2, rgV3;

  union PU { unsigned u[4]; bf16x8 v; };
  union VU { int2 d2[2]; bf16x8 v; };

#define LOADT(t_) {                                                               \
    const unsigned short* k_ = kSrc + (t_) * 64 * HD;                             \
    rgK0 = *(const int4*)k_;                                                      \
    rgK1 = *(const int4*)(k_ + 16 * HD);                                          \
    rgK2 = *(const int4*)(k_ + 32 * HD);                                          \
    rgK3 = *(const int4*)(k_ + 48 * HD);                                          \
    const unsigned short* v_ = vSrc + (t_) * 64;                                  \
    rgV0 = *(const int4*)v_;                                                      \
    rgV1 = *(const int4*)(v_ + (size_t)8 * T_);                                   \
    rgV2 = *(const int4*)(v_ + (size_t)16 * T_);                                  \
    rgV3 = *(const int4*)(v_ + (size_t)24 * T_);                                  \
  }

#define STORET() {                                                               \
    *(int4*)kD = rgK0;                                                           \
    *(int4*)(kD + 16 * 40) = rgK1;                                               \
    *(int4*)(kD + 32 * 40) = rgK2;                                               \
    *(int4*)(kD + 48 * 40) = rgK3;                                               \
    *(int4*)vD = rgV0;                                                           \
    *(int4*)(vD + 8 * 72) = rgV1;                                                \
    *(int4*)(vD + 16 * 72) = rgV2;                                               \
    *(int4*)(vD + 24 * 72) = rgV3;                                               \
  }

// QK -> exp -> pack (lane-local) -> PV through registers. kappa(g4,j) = 4g4+(j&3)+16(j>>2).
#define SUBTILE(qf, lsum, acc0, acc1) {                                           \
    f32x4 z = {};                                                                 \
    f32x4 s0 = __builtin_amdgcn_mfma_f32_16x16x32_bf16(kf0, qf, z, 0, 0, 0);      \
    f32x4 s1 = __builtin_amdgcn_mfma_f32_16x16x32_bf16(kf1, qf, z, 0, 0, 0);      \
    f32x4 s2 = __builtin_amdgcn_mfma_f32_16x16x32_bf16(kf2, qf, z, 0, 0, 0);      \
    f32x4 s3 = __builtin_amdgcn_mfma_f32_16x16x32_bf16(kf3, qf, z, 0, 0, 0);      \
    float p0 = fexp2(s0[0]), p1 = fexp2(s0[1]), p2 = fexp2(s0[2]), p3 = fexp2(s0[3]); \
    float p4 = fexp2(s1[0]), p5 = fexp2(s1[1]), p6 = fexp2(s1[2]), p7 = fexp2(s1[3]); \
    float p8 = fexp2(s2[0]), p9 = fexp2(s2[1]), pa = fexp2(s2[2]), pb = fexp2(s2[3]); \
    float pc = fexp2(s3[0]), pd = fexp2(s3[1]), pe = fexp2(s3[2]), pf = fexp2(s3[3]); \
    float ps = ((p0 + p1) + (p2 + p3)) + ((p4 + p5) + (p6 + p7)) +                \
               ((p8 + p9) + (pa + pb)) + ((pc + pd) + (pe + pf));                 \
    PU w0, w1;                                                                    \
    w0.u[0] = cvtpk(p0, p1); w0.u[1] = cvtpk(p2, p3);                             \
    w0.u[2] = cvtpk(p4, p5); w0.u[3] = cvtpk(p6, p7);                             \
    w1.u[0] = cvtpk(p8, p9); w1.u[1] = cvtpk(pa, pb);                             \
    w1.u[2] = cvtpk(pc, pd); w1.u[3] = cvtpk(pe, pf);                             \
    ps += __shfl_xor(ps, 16);                                                     \
    ps += __shfl_xor(ps, 32);                                                     \
    lsum += ps;                                                                   \
    acc0 = __builtin_amdgcn_mfma_f32_16x16x32_bf16(vf00.v, w0.v, acc0, 0, 0, 0);  \
    acc1 = __builtin_amdgcn_mfma_f32_16x16x32_bf16(vf01.v, w0.v, acc1, 0, 0, 0);  \
    acc0 = __builtin_amdgcn_mfma_f32_16x16x32_bf16(vf10.v, w1.v, acc0, 0, 0, 0);  \
    acc1 = __builtin_amdgcn_mfma_f32_16x16x32_bf16(vf11.v, w1.v, acc1, 0, 0, 0);  \
  }

  // prologue: stage tile 0
  LOADT(0)
  STORET()

  for (int t = 0; t < 36; ++t) {
    if (t < 35) LOADT(t + 1)            // global -> staging regs, in flight over compute

    // fragment reads (ordered before the STORET below by in-order DS pipeline)
    bf16x8 kf0 = *(const bf16x8*)&Ks[(r16) * 40 + g4 * 8];
    bf16x8 kf1 = *(const bf16x8*)&Ks[(16 + r16) * 40 + g4 * 8];
    bf16x8 kf2 = *(const bf16x8*)&Ks[(32 + r16) * 40 + g4 * 8];
    bf16x8 kf3 = *(const bf16x8*)&Ks[(48 + r16) * 40 + g4 * 8];
    VU vf00, vf01, vf10, vf11;
    {
      const short* vr0 = &Vs[r16 * 72];
      const short* vr1 = &Vs[(16 + r16) * 72];
      vf00.d2[0] = *(const int2*)(vr0 + 4 * g4);
      vf00.d2[1] = *(const int2*)(vr0 + 16 + 4 * g4);
      vf01.d2[0] = *(const int2*)(vr1 + 4 * g4);
      vf01.d2[1] = *(const int2*)(vr1 + 16 + 4 * g4);
      vf10.d2[0] = *(const int2*)(vr0 + 32 + 4 * g4);
      vf10.d2[1] = *(const int2*)(vr0 + 48 + 4 * g4);
      vf11.d2[0] = *(const int2*)(vr1 + 32 + 4 * g4);
      vf11.d2[1] = *(const int2*)(vr1 + 48 + 4 * g4);
    }

    SUBTILE(qfA, lA, accA0, accA1)
    SUBTILE(qfB, lB, accB0, accB1)

    if (t < 35) STORET()                // write tile t+1 (after this tile's reads)
  }

  // output: O[d][q] with q = r16 (lane-local l sums), d = dh*16 + 4g4 + r
  float invA = 1.f / lA;
  float invB = 1.f / lB;
  unsigned short* oA = attnT + ((size_t)b * T_ + qbase + r16) * C_ + h * HD + 4 * g4;
  unsigned short* oB = attnT + ((size_t)b * T_ + qbase + 16 + r16) * C_ + h * HD + 4 * g4;
  {
    u32x2 wA0 = {cvtpk(accA0[0] * invA, accA0[1] * invA), cvtpk(accA0[2] * invA, accA0[3] * invA)};
    u32x2 wA1 = {cvtpk(accA1[0] * invA, accA1[1] * invA), cvtpk(accA1[2] * invA, accA1[3] * invA)};
    u32x2 wB0 = {cvtpk(accB0[0] * invB, accB0[1] * invB), cvtpk(accB0[2] * invB, accB0[3] * invB)};
    u32x2 wB1 = {cvtpk(accB1[0] * invB, accB1[1] * invB), cvtpk(accB1[2] * invB, accB1[3] * invB)};
    *(u32x2*)oA = wA0;
    *(u32x2*)(oA + 16) = wA1;
    *(u32x2*)oB = wB0;
    *(u32x2*)(oB + 16) = wB1;
  }
#undef LOADT
#undef STORET
#undef SUBTILE
}

// ---------------- proj GEMM + bias + residual ----------------
__global__ __launch_bounds__(256) void proj_gemm(const unsigned short* W, const unsigned short* aT,
                                                 const float* bias, const float* x, float* out) {
  int b = blockIdx.z;
  int lane = threadIdx.x & 63, w = threadIdx.x >> 6;
  int r16 = lane & 15, g4 = lane >> 4;
  int m0 = blockIdx.y * 64 + (w >> 1) * 32;
  int n0 = blockIdx.x * 64 + (w & 1) * 32;
  const bf16x8* Wv = (const bf16x8*)W;
  const bf16x8* Av = (const bf16x8*)(aT + (size_t)b * T_ * C_);
  f32x4 acc[2][2] = {};
  for (int k0 = 0; k0 < C_; k0 += 32) {
    bf16x8 af[2], bfr[2];
    for (int mi = 0; mi < 2; ++mi)
      af[mi] = Wv[((m0 + mi * 16 + r16) * C_ + k0 + g4 * 8) >> 3];
    for (int ni = 0; ni < 2; ++ni)
      bfr[ni] = Av[((n0 + ni * 16 + r16) * C_ + k0 + g4 * 8) >> 3];
    for (int mi = 0; mi < 2; ++mi)
      for (int ni = 0; ni < 2; ++ni)
        acc[mi][ni] = __builtin_amdgcn_mfma_f32_16x16x32_bf16(af[mi], bfr[ni], acc[mi][ni], 0, 0, 0);
  }
  for (int mi = 0; mi < 2; ++mi)
    for (int ni = 0; ni < 2; ++ni) {
      int t = n0 + ni * 16 + r16;
      for (int r = 0; r < 4; ++r) {
        int o = m0 + mi * 16 + g4 * 4 + r;
        size_t idx = ((size_t)b * C_ + o) * T_ + t;
        out[idx] = x[idx] + acc[mi][ni][r] + bias[o];
      }
    }
}

extern "C" void kernel_launch(void* const* d_in, const int* in_sizes, int n_in,
                              void* d_out, int out_size, void* d_ws, size_t ws_size,
                              hipStream_t stream) {
  const float* x  = (const float*)d_in[0];
  const float* gw = (const float*)d_in[1];
  const float* gb = (const float*)d_in[2];
  const float* wq = (const float*)d_in[3];
  const float* bq = (const float*)d_in[4];
  const float* wp = (const float*)d_in[5];
  const float* bp = (const float*)d_in[6];

  char* ws = (char*)d_ws;
  float* ws1 = (float*)ws;                       // 256*2 f32
  unsigned short* wqb = (unsigned short*)(ws + 4096);
  unsigned short* wpb = wqb + 3 * C_ * C_;
  unsigned short* nT  = wpb + C_ * C_;
  const size_t NE = (size_t)B_ * T_ * C_;        // 2359296
  unsigned short* qT = nT + NE;
  unsigned short* kT = qT + NE;
  unsigned short* vW = kT + NE;
  unsigned short* aT = vW + NE;

  prep<<<1280, 256, 0, stream>>>(wq, wp, x, wqb, wpb, ws1);
  gn_norm<<<dim3(72, 4), 256, 0, stream>>>(x, ws1, gw, gb, nT);
  qkv_gemm<<<dim3(36, 12, 4), 256, 0, stream>>>(wqb, nT, bq, qT, kT, vW);
  attn<<<dim3(72, 8, 4), 64, 0, stream>>>(qT, kT, vW, aT);
  proj_gemm<<<dim3(36, 4, 4), 256, 0, stream>>>(wpb, aT, bp, x, (float*)d_out);
}

// Round 14
// 114.967 us; speedup vs baseline: 1.5750x; 1.0338x over previous
//
#include <hip/hip_runtime.h>

#define B_ 4
#define C_ 256
#define T_ 2304
#define HD 32
#define GSZ (32 * T_)                 // elems per groupnorm group = 73728
#define SCL2E (0.17677669529663687f * 1.44269504088896f)  // (1/sqrt(32)) * log2(e)

typedef short bf16x8 __attribute__((ext_vector_type(8)));
typedef float f32x4 __attribute__((ext_vector_type(4)));
typedef unsigned int u32x2 __attribute__((ext_vector_type(2)));

__device__ inline unsigned short f2bf(float f) {
  unsigned int u = __float_as_uint(f);
  return (unsigned short)((u + 0x7FFFu + ((u >> 16) & 1u)) >> 16);
}

__device__ inline float fexp2(float x) {
  float r;
  asm("v_exp_f32 %0, %1" : "=v"(r) : "v"(x));
  return r;
}

__device__ inline unsigned cvtpk(float lo, float hi) {
  unsigned r;
  asm("v_cvt_pk_bf16_f32 %0, %1, %2" : "=v"(r) : "v"(lo), "v"(hi));
  return r;
}

// ---------------- weights -> bf16  +  groupnorm partial stats (merged) ----------------
__global__ void prep(const float* wq, const float* wp, const float* x,
                     unsigned short* oq, unsigned short* op, float* ws1) {
  if (blockIdx.x < 1024) {
    int i = blockIdx.x * 256 + threadIdx.x;
    const int n1 = 3 * C_ * C_;
    if (i < n1) oq[i] = f2bf(wq[i]);
    else        op[i - n1] = f2bf(wp[i - n1]);
    return;
  }
  int bid = blockIdx.x - 1024;
  int bg = bid >> 3, sl = bid & 7;
  const float4* p = (const float4*)(x + (size_t)bg * GSZ + sl * (GSZ / 8));
  float s = 0.f, q = 0.f;
  for (int it = 0; it < 9; ++it) {
    float4 v = p[it * 256 + threadIdx.x];
    s += v.x + v.y + v.z + v.w;
    q += v.x * v.x + v.y * v.y + v.z * v.z + v.w * v.w;
  }
  for (int off = 32; off; off >>= 1) {
    s += __shfl_down(s, off);
    q += __shfl_down(q, off);
  }
  __shared__ float red[8];
  int w = threadIdx.x >> 6;
  if ((threadIdx.x & 63) == 0) { red[w * 2] = s; red[w * 2 + 1] = q; }
  __syncthreads();
  if (threadIdx.x == 0) {
    float S = red[0] + red[2] + red[4] + red[6];
    float Q = red[1] + red[3] + red[5] + red[7];
    ws1[bid * 2] = S;
    ws1[bid * 2 + 1] = Q;
  }
}

// ---------------- groupnorm: finalize stats (inline) + normalize + transpose to nT[B][T][C] --
__global__ void gn_norm(const float* x, const float* ws1, const float* gamma,
                        const float* beta, unsigned short* nT) {
  int b = blockIdx.y, t0 = blockIdx.x * 32;
  __shared__ unsigned short tile[32 * 264];
  __shared__ float stl[16];
  int tid = threadIdx.x;
  if (tid < 8) {
    float S = 0.f, Q = 0.f;
    for (int sl = 0; sl < 8; ++sl) {
      S += ws1[((b * 8 + tid) * 8 + sl) * 2];
      Q += ws1[((b * 8 + tid) * 8 + sl) * 2 + 1];
    }
    float mean = S / (float)GSZ;
    float var = Q / (float)GSZ - mean * mean;
    stl[tid * 2] = mean;
    stl[tid * 2 + 1] = rsqrtf(var + 1e-5f);
  }
  __syncthreads();
#pragma unroll
  for (int it = 0; it < 8; ++it) {
    int qd = it * 256 + tid;
    int c = qd >> 3, tq = qd & 7;
    float4 v = *(const float4*)&x[((size_t)b * C_ + c) * T_ + t0 + tq * 4];
    int g = c >> 5;
    float mean = stl[g * 2], rstd = stl[g * 2 + 1];
    float sc = rstd * gamma[c];
    float sh = beta[c] - mean * sc;
    tile[(tq * 4 + 0) * 264 + c] = f2bf(v.x * sc + sh);
    tile[(tq * 4 + 1) * 264 + c] = f2bf(v.y * sc + sh);
    tile[(tq * 4 + 2) * 264 + c] = f2bf(v.z * sc + sh);
    tile[(tq * 4 + 3) * 264 + c] = f2bf(v.w * sc + sh);
  }
  __syncthreads();
#pragma unroll
  for (int it = 0; it < 4; ++it) {
    int qd = it * 256 + tid;
    int tt = qd >> 5, c8 = (qd & 31) * 8;
    *(uint4*)&nT[((size_t)b * T_ + t0 + tt) * C_ + c8] = *(const uint4*)&tile[tt * 264 + c8];
  }
}

// ---------------- QKV GEMM: [768,256] x nT -> qT/kT [b,h,t,d], v [b,h,d,t] ----------------
// Coalesced epilogue: acc -> LDS transpose tile -> 16B stores. Each block handles one of
// q/k/v exclusively (blockIdx.y: 0-3=q, 4-7=k, 8-11=v). q pre-scaled by SCL2E.
__global__ __launch_bounds__(256) void qkv_gemm(const unsigned short* W, const unsigned short* nT,
                                                const float* bias, unsigned short* qT,
                                                unsigned short* kT, unsigned short* vW) {
  __shared__ unsigned short tt[64][72];
  int b = blockIdx.z;
  int lane = threadIdx.x & 63, w = threadIdx.x >> 6;
  int r16 = lane & 15, g4 = lane >> 4;
  int y = blockIdx.y;
  int type = y >> 2;                    // 0=q 1=k 2=v
  int m0 = y * 64 + (w >> 1) * 32;
  int n0 = blockIdx.x * 64 + (w & 1) * 32;
  const bf16x8* Wv = (const bf16x8*)W;
  const bf16x8* Nv = (const bf16x8*)(nT + (size_t)b * T_ * C_);
  f32x4 acc[2][2] = {};
  for (int k0 = 0; k0 < C_; k0 += 32) {
    bf16x8 af[2], bfr[2];
    for (int mi = 0; mi < 2; ++mi)
      af[mi] = Wv[((m0 + mi * 16 + r16) * C_ + k0 + g4 * 8) >> 3];
    for (int ni = 0; ni < 2; ++ni)
      bfr[ni] = Nv[((n0 + ni * 16 + r16) * C_ + k0 + g4 * 8) >> 3];
    for (int mi = 0; mi < 2; ++mi)
      for (int ni = 0; ni < 2; ++ni)
        acc[mi][ni] = __builtin_amdgcn_mfma_f32_16x16x32_bf16(af[mi], bfr[ni], acc[mi][ni], 0, 0, 0);
  }
#pragma unroll
  for (int mi = 0; mi < 2; ++mi) {
#pragma unroll
    for (int ni = 0; ni < 2; ++ni) {
      int t_loc = (w & 1) * 32 + ni * 16 + r16;
      int o_loc = (w >> 1) * 32 + mi * 16 + g4 * 4;
      int o = y * 64 + o_loc;
      float v0 = acc[mi][ni][0] + bias[o + 0];
      float v1 = acc[mi][ni][1] + bias[o + 1];
      float v2 = acc[mi][ni][2] + bias[o + 2];
      float v3 = acc[mi][ni][3] + bias[o + 3];
      if (type == 0) { v0 *= SCL2E; v1 *= SCL2E; v2 *= SCL2E; v3 *= SCL2E; }
      if (type < 2) {
        u32x2 pw = {cvtpk(v0, v1), cvtpk(v2, v3)};
        *(u32x2*)&tt[t_loc][o_loc] = pw;          // [t][o]
      } else {
        tt[o_loc + 0][t_loc] = f2bf(v0);          // [o][t]
        tt[o_loc + 1][t_loc] = f2bf(v1);
        tt[o_loc + 2][t_loc] = f2bf(v2);
        tt[o_loc + 3][t_loc] = f2bf(v3);
      }
    }
  }
  __syncthreads();
  int tid = threadIdx.x;
  if (type < 2) {
    unsigned short* dst = (type == 0) ? qT : kT;
    int obase = y * 64 - type * 256;
    int t_loc = tid >> 2;
    int tg = blockIdx.x * 64 + t_loc;
#pragma unroll
    for (int half = 0; half < 2; ++half) {
      int o_loc = half * 32 + (tid & 3) * 8;
      int o2 = obase + o_loc;
      int hh = o2 >> 5, d = o2 & 31;
      *(uint4*)&dst[(((size_t)b * 8 + hh) * T_ + tg) * HD + d] = *(const uint4*)&tt[t_loc][o_loc];
    }
  } else {
    int obase = y * 64 - 512;
    int o_loc = tid >> 2;
    int o2 = obase + o_loc;
    int hh = o2 >> 5, d = o2 & 31;
    unsigned short* vdst = vW + ((size_t)(b * 8 + hh) * HD + d) * T_ + blockIdx.x * 64;
#pragma unroll
    for (int half = 0; half < 2; ++half) {
      int t_loc = half * 32 + (tid & 3) * 8;
      *(uint4*)&vdst[t_loc] = *(const uint4*)&tt[o_loc][t_loc];
    }
  }
}

// ---------------- flash attention: R8 structure, 16 q-rows per wave (2x occupancy) ---------
// 2 waves/block share a double-buffered K/V tile; each wave owns 16 q-rows. kappa-paired
// register PV (no P-LDS). Staging regs hold tile t+1 (LDS) and t+2 (global) in flight.
__global__ __launch_bounds__(128) void attn(const unsigned short* qT, const unsigned short* kT,
                                            const unsigned short* vW, unsigned short* attnT) {
  int b = blockIdx.z, h = blockIdx.y, qt = blockIdx.x;   // qt 0..71, 32 q-rows per block
  int tid = threadIdx.x, lane = tid & 63, w = tid >> 6;  // w in {0,1}
  int r16 = lane & 15, g4 = lane >> 4;
  __shared__ short Ks[2][64 * 40];   // [s][d] padded to 40, double-buffered
  __shared__ short Vs[2][32 * 72];   // [d][s] padded to 72, double-buffered
  const unsigned short* qB = qT + ((size_t)b * 8 + h) * T_ * HD;
  const unsigned short* kB = kT + ((size_t)b * 8 + h) * T_ * HD;
  const unsigned short* vB = vW + ((size_t)b * 8 + h) * HD * T_;
  int qbase = qt * 32 + w * 16;      // wave owns q-rows [qbase, qbase+16)
  bf16x8 qf = *(const bf16x8*)(qB + (qbase + r16) * HD + g4 * 8);
  float lsum = 0.f;
  f32x4 acc0 = {}, acc1 = {};

  // cooperative staging: 128 threads, 4x b128 each
  int krow = tid >> 2, kcol = (tid & 3) * 8;   // K rows krow, krow+32
  int vrow = tid >> 3, vcol = (tid & 7) * 8;   // V rows vrow, vrow+16
  const unsigned short* kSrc = kB + (size_t)krow * HD + kcol;
  const unsigned short* vSrc = vB + (size_t)vrow * T_ + vcol;
  int4 rgK0, rgK1, rgV0, rgV1;

  union PU { unsigned u[4]; bf16x8 v; };
  union VU { int2 d2[2]; bf16x8 v; };

#define LOADT(t_) {                                                               \
    const unsigned short* k_ = kSrc + (t_) * 64 * HD;                             \
    rgK0 = *(const int4*)k_;                                                      \
    rgK1 = *(const int4*)(k_ + 32 * HD);                                          \
    const unsigned short* v_ = vSrc + (t_) * 64;                                  \
    rgV0 = *(const int4*)v_;                                                      \
    rgV1 = *(const int4*)(v_ + (size_t)16 * T_);                                  \
  }

#define STORET(bi) {                                                              \
    short* kD = &Ks[bi][krow * 40 + kcol];                                        \
    *(int4*)kD = rgK0;                                                            \
    *(int4*)(kD + 32 * 40) = rgK1;                                                \
    short* vD = &Vs[bi][vrow * 72 + vcol];                                        \
    *(int4*)vD = rgV0;                                                            \
    *(int4*)(vD + 16 * 72) = rgV1;                                                \
  }

  // prologue: tile0 -> LDS buf0, tile1 -> regs
  LOADT(0)
  STORET(0)
  LOADT(1)
  __syncthreads();

  for (int t = 0; t < 36; ++t) {
    int bi = t & 1;
    if (t < 35) STORET(bi ^ 1)          // tile t+1: regs -> other buffer
    if (t < 34) LOADT(t + 2)            // tile t+2: global -> regs

    const short* Kc = &Ks[bi][0];
    const short* Vc = &Vs[bi][0];
    // K fragments (A-operand rows s)
    bf16x8 kf0 = *(const bf16x8*)&Kc[(r16) * 40 + g4 * 8];
    bf16x8 kf1 = *(const bf16x8*)&Kc[(16 + r16) * 40 + g4 * 8];
    bf16x8 kf2 = *(const bf16x8*)&Kc[(32 + r16) * 40 + g4 * 8];
    bf16x8 kf3 = *(const bf16x8*)&Kc[(48 + r16) * 40 + g4 * 8];
    // V fragments, kappa' = 32kh + 4g4+(j&3)+16(j>>2); rows d = dh*16+r16
    VU vf00, vf01, vf10, vf11;
    {
      const short* vr0 = Vc + r16 * 72;
      const short* vr1 = Vc + (16 + r16) * 72;
      vf00.d2[0] = *(const int2*)(vr0 + 4 * g4);
      vf00.d2[1] = *(const int2*)(vr0 + 16 + 4 * g4);
      vf01.d2[0] = *(const int2*)(vr1 + 4 * g4);
      vf01.d2[1] = *(const int2*)(vr1 + 16 + 4 * g4);
      vf10.d2[0] = *(const int2*)(vr0 + 32 + 4 * g4);
      vf10.d2[1] = *(const int2*)(vr0 + 48 + 4 * g4);
      vf11.d2[0] = *(const int2*)(vr1 + 32 + 4 * g4);
      vf11.d2[1] = *(const int2*)(vr1 + 48 + 4 * g4);
    }

    // QK -> exp -> pack (lane-local) -> PV through registers.
    {
      f32x4 z = {};
      f32x4 s0 = __builtin_amdgcn_mfma_f32_16x16x32_bf16(kf0, qf, z, 0, 0, 0);
      f32x4 s1 = __builtin_amdgcn_mfma_f32_16x16x32_bf16(kf1, qf, z, 0, 0, 0);
      f32x4 s2 = __builtin_amdgcn_mfma_f32_16x16x32_bf16(kf2, qf, z, 0, 0, 0);
      f32x4 s3 = __builtin_amdgcn_mfma_f32_16x16x32_bf16(kf3, qf, z, 0, 0, 0);
      float p0 = fexp2(s0[0]), p1 = fexp2(s0[1]), p2 = fexp2(s0[2]), p3 = fexp2(s0[3]);
      float p4 = fexp2(s1[0]), p5 = fexp2(s1[1]), p6 = fexp2(s1[2]), p7 = fexp2(s1[3]);
      float p8 = fexp2(s2[0]), p9 = fexp2(s2[1]), pa = fexp2(s2[2]), pb = fexp2(s2[3]);
      float pc = fexp2(s3[0]), pd = fexp2(s3[1]), pe = fexp2(s3[2]), pf = fexp2(s3[3]);
      float ps = ((p0 + p1) + (p2 + p3)) + ((p4 + p5) + (p6 + p7)) +
                 ((p8 + p9) + (pa + pb)) + ((pc + pd) + (pe + pf));
      PU w0, w1;
      w0.u[0] = cvtpk(p0, p1); w0.u[1] = cvtpk(p2, p3);
      w0.u[2] = cvtpk(p4, p5); w0.u[3] = cvtpk(p6, p7);
      w1.u[0] = cvtpk(p8, p9); w1.u[1] = cvtpk(pa, pb);
      w1.u[2] = cvtpk(pc, pd); w1.u[3] = cvtpk(pe, pf);
      ps += __shfl_xor(ps, 16);
      ps += __shfl_xor(ps, 32);
      lsum += ps;
      acc0 = __builtin_amdgcn_mfma_f32_16x16x32_bf16(vf00.v, w0.v, acc0, 0, 0, 0);
      acc1 = __builtin_amdgcn_mfma_f32_16x16x32_bf16(vf01.v, w0.v, acc1, 0, 0, 0);
      acc0 = __builtin_amdgcn_mfma_f32_16x16x32_bf16(vf10.v, w1.v, acc0, 0, 0, 0);
      acc1 = __builtin_amdgcn_mfma_f32_16x16x32_bf16(vf11.v, w1.v, acc1, 0, 0, 0);
    }

    __syncthreads();                    // tile t consumed; tile t+1 stores visible
  }

  // output: O[d][q] with q = r16 (lane-local l sum), d = dh*16 + 4g4 + r
  float inv = 1.f / lsum;
  unsigned short* oA = attnT + ((size_t)b * T_ + qbase + r16) * C_ + h * HD + 4 * g4;
  {
    u32x2 w0 = {cvtpk(acc0[0] * inv, acc0[1] * inv), cvtpk(acc0[2] * inv, acc0[3] * inv)};
    u32x2 w1 = {cvtpk(acc1[0] * inv, acc1[1] * inv), cvtpk(acc1[2] * inv, acc1[3] * inv)};
    *(u32x2*)oA = w0;
    *(u32x2*)(oA + 16) = w1;
  }
#undef LOADT
#undef STORET
}

// ---------------- proj GEMM + bias + residual ----------------
__global__ __launch_bounds__(256) void proj_gemm(const unsigned short* W, const unsigned short* aT,
                                                 const float* bias, const float* x, float* out) {
  int b = blockIdx.z;
  int lane = threadIdx.x & 63, w = threadIdx.x >> 6;
  int r16 = lane & 15, g4 = lane >> 4;
  int m0 = blockIdx.y * 64 + (w >> 1) * 32;
  int n0 = blockIdx.x * 64 + (w & 1) * 32;
  const bf16x8* Wv = (const bf16x8*)W;
  const bf16x8* Av = (const bf16x8*)(aT + (size_t)b * T_ * C_);
  f32x4 acc[2][2] = {};
  for (int k0 = 0; k0 < C_; k0 += 32) {
    bf16x8 af[2], bfr[2];
    for (int mi = 0; mi < 2; ++mi)
      af[mi] = Wv[((m0 + mi * 16 + r16) * C_ + k0 + g4 * 8) >> 3];
    for (int ni = 0; ni < 2; ++ni)
      bfr[ni] = Av[((n0 + ni * 16 + r16) * C_ + k0 + g4 * 8) >> 3];
    for (int mi = 0; mi < 2; ++mi)
      for (int ni = 0; ni < 2; ++ni)
        acc[mi][ni] = __builtin_amdgcn_mfma_f32_16x16x32_bf16(af[mi], bfr[ni], acc[mi][ni], 0, 0, 0);
  }
  for (int mi = 0; mi < 2; ++mi)
    for (int ni = 0; ni < 2; ++ni) {
      int t = n0 + ni * 16 + r16;
      for (int r = 0; r < 4; ++r) {
        int o = m0 + mi * 16 + g4 * 4 + r;
        size_t idx = ((size_t)b * C_ + o) * T_ + t;
        out[idx] = x[idx] + acc[mi][ni][r] + bias[o];
      }
    }
}

extern "C" void kernel_launch(void* const* d_in, const int* in_sizes, int n_in,
                              void* d_out, int out_size, void* d_ws, size_t ws_size,
                              hipStream_t stream) {
  const float* x  = (const float*)d_in[0];
  const float* gw = (const float*)d_in[1];
  const float* gb = (const float*)d_in[2];
  const float* wq = (const float*)d_in[3];
  const float* bq = (const float*)d_in[4];
  const float* wp = (const float*)d_in[5];
  const float* bp = (const float*)d_in[6];

  char* ws = (char*)d_ws;
  float* ws1 = (float*)ws;                       // 256*2 f32
  unsigned short* wqb = (unsigned short*)(ws + 4096);
  unsigned short* wpb = wqb + 3 * C_ * C_;
  unsigned short* nT  = wpb + C_ * C_;
  const size_t NE = (size_t)B_ * T_ * C_;        // 2359296
  unsigned short* qT = nT + NE;
  unsigned short* kT = qT + NE;
  unsigned short* vW = kT + NE;
  unsigned short* aT = vW + NE;

  prep<<<1280, 256, 0, stream>>>(wq, wp, x, wqb, wpb, ws1);
  gn_norm<<<dim3(72, 4), 256, 0, stream>>>(x, ws1, gw, gb, nT);
  qkv_gemm<<<dim3(36, 12, 4), 256, 0, stream>>>(wqb, nT, bq, qT, kT, vW);
  attn<<<dim3(72, 8, 4), 128, 0, stream>>>(qT, kT, vW, aT);
  proj_gemm<<<dim3(36, 4, 4), 256, 0, stream>>>(wpb, aT, bp, x, (float*)d_out);
}

// Round 15
// 107.854 us; speedup vs baseline: 1.6788x; 1.0659x over previous
//
#include <hip/hip_runtime.h>

#define B_ 4
#define C_ 256
#define T_ 2304
#define HD 32
#define GSZ (32 * T_)                 // elems per groupnorm group = 73728
#define SCL2E (0.17677669529663687f * 1.44269504088896f)  // (1/sqrt(32)) * log2(e)

typedef short bf16x8 __attribute__((ext_vector_type(8)));
typedef float f32x4 __attribute__((ext_vector_type(4)));
typedef unsigned int u32x2 __attribute__((ext_vector_type(2)));

__device__ inline unsigned short f2bf(float f) {
  unsigned int u = __float_as_uint(f);
  return (unsigned short)((u + 0x7FFFu + ((u >> 16) & 1u)) >> 16);
}

__device__ inline float fexp2(float x) {
  float r;
  asm("v_exp_f32 %0, %1" : "=v"(r) : "v"(x));
  return r;
}

__device__ inline unsigned cvtpk(float lo, float hi) {
  unsigned r;
  asm("v_cvt_pk_bf16_f32 %0, %1, %2" : "=v"(r) : "v"(lo), "v"(hi));
  return r;
}

// ---------------- weights -> bf16  +  groupnorm partial stats (merged) ----------------
__global__ void prep(const float* wq, const float* wp, const float* x,
                     unsigned short* oq, unsigned short* op, float* ws1) {
  if (blockIdx.x < 1024) {
    int i = blockIdx.x * 256 + threadIdx.x;
    const int n1 = 3 * C_ * C_;
    if (i < n1) oq[i] = f2bf(wq[i]);
    else        op[i - n1] = f2bf(wp[i - n1]);
    return;
  }
  int bid = blockIdx.x - 1024;
  int bg = bid >> 3, sl = bid & 7;
  const float4* p = (const float4*)(x + (size_t)bg * GSZ + sl * (GSZ / 8));
  float s = 0.f, q = 0.f;
  for (int it = 0; it < 9; ++it) {
    float4 v = p[it * 256 + threadIdx.x];
    s += v.x + v.y + v.z + v.w;
    q += v.x * v.x + v.y * v.y + v.z * v.z + v.w * v.w;
  }
  for (int off = 32; off; off >>= 1) {
    s += __shfl_down(s, off);
    q += __shfl_down(q, off);
  }
  __shared__ float red[8];
  int w = threadIdx.x >> 6;
  if ((threadIdx.x & 63) == 0) { red[w * 2] = s; red[w * 2 + 1] = q; }
  __syncthreads();
  if (threadIdx.x == 0) {
    float S = red[0] + red[2] + red[4] + red[6];
    float Q = red[1] + red[3] + red[5] + red[7];
    ws1[bid * 2] = S;
    ws1[bid * 2 + 1] = Q;
  }
}

// ---------------- groupnorm: finalize stats (inline) + normalize + transpose to nT[B][T][C] --
__global__ void gn_norm(const float* x, const float* ws1, const float* gamma,
                        const float* beta, unsigned short* nT) {
  int b = blockIdx.y, t0 = blockIdx.x * 32;
  __shared__ unsigned short tile[32 * 264];
  __shared__ float stl[16];
  int tid = threadIdx.x;
  if (tid < 8) {
    float S = 0.f, Q = 0.f;
    for (int sl = 0; sl < 8; ++sl) {
      S += ws1[((b * 8 + tid) * 8 + sl) * 2];
      Q += ws1[((b * 8 + tid) * 8 + sl) * 2 + 1];
    }
    float mean = S / (float)GSZ;
    float var = Q / (float)GSZ - mean * mean;
    stl[tid * 2] = mean;
    stl[tid * 2 + 1] = rsqrtf(var + 1e-5f);
  }
  __syncthreads();
#pragma unroll
  for (int it = 0; it < 8; ++it) {
    int qd = it * 256 + tid;
    int c = qd >> 3, tq = qd & 7;
    float4 v = *(const float4*)&x[((size_t)b * C_ + c) * T_ + t0 + tq * 4];
    int g = c >> 5;
    float mean = stl[g * 2], rstd = stl[g * 2 + 1];
    float sc = rstd * gamma[c];
    float sh = beta[c] - mean * sc;
    tile[(tq * 4 + 0) * 264 + c] = f2bf(v.x * sc + sh);
    tile[(tq * 4 + 1) * 264 + c] = f2bf(v.y * sc + sh);
    tile[(tq * 4 + 2) * 264 + c] = f2bf(v.z * sc + sh);
    tile[(tq * 4 + 3) * 264 + c] = f2bf(v.w * sc + sh);
  }
  __syncthreads();
#pragma unroll
  for (int it = 0; it < 4; ++it) {
    int qd = it * 256 + tid;
    int tt = qd >> 5, c8 = (qd & 31) * 8;
    *(uint4*)&nT[((size_t)b * T_ + t0 + tt) * C_ + c8] = *(const uint4*)&tile[tt * 264 + c8];
  }
}

// ---------------- QKV GEMM: [768,256] x nT -> qT/kT [b,h,t,d], v [b,h,d,t] ----------------
__global__ __launch_bounds__(256) void qkv_gemm(const unsigned short* W, const unsigned short* nT,
                                                const float* bias, unsigned short* qT,
                                                unsigned short* kT, unsigned short* vW) {
  __shared__ unsigned short tt[64][72];
  int b = blockIdx.z;
  int lane = threadIdx.x & 63, w = threadIdx.x >> 6;
  int r16 = lane & 15, g4 = lane >> 4;
  int y = blockIdx.y;
  int type = y >> 2;                    // 0=q 1=k 2=v
  int m0 = y * 64 + (w >> 1) * 32;
  int n0 = blockIdx.x * 64 + (w & 1) * 32;
  const bf16x8* Wv = (const bf16x8*)W;
  const bf16x8* Nv = (const bf16x8*)(nT + (size_t)b * T_ * C_);
  f32x4 acc[2][2] = {};
  for (int k0 = 0; k0 < C_; k0 += 32) {
    bf16x8 af[2], bfr[2];
    for (int mi = 0; mi < 2; ++mi)
      af[mi] = Wv[((m0 + mi * 16 + r16) * C_ + k0 + g4 * 8) >> 3];
    for (int ni = 0; ni < 2; ++ni)
      bfr[ni] = Nv[((n0 + ni * 16 + r16) * C_ + k0 + g4 * 8) >> 3];
    for (int mi = 0; mi < 2; ++mi)
      for (int ni = 0; ni < 2; ++ni)
        acc[mi][ni] = __builtin_amdgcn_mfma_f32_16x16x32_bf16(af[mi], bfr[ni], acc[mi][ni], 0, 0, 0);
  }
#pragma unroll
  for (int mi = 0; mi < 2; ++mi) {
#pragma unroll
    for (int ni = 0; ni < 2; ++ni) {
      int t_loc = (w & 1) * 32 + ni * 16 + r16;
      int o_loc = (w >> 1) * 32 + mi * 16 + g4 * 4;
      int o = y * 64 + o_loc;
      float v0 = acc[mi][ni][0] + bias[o + 0];
      float v1 = acc[mi][ni][1] + bias[o + 1];
      float v2 = acc[mi][ni][2] + bias[o + 2];
      float v3 = acc[mi][ni][3] + bias[o + 3];
      if (type == 0) { v0 *= SCL2E; v1 *= SCL2E; v2 *= SCL2E; v3 *= SCL2E; }
      if (type < 2) {
        u32x2 pw = {cvtpk(v0, v1), cvtpk(v2, v3)};
        *(u32x2*)&tt[t_loc][o_loc] = pw;          // [t][o]
      } else {
        tt[o_loc + 0][t_loc] = f2bf(v0);          // [o][t]
        tt[o_loc + 1][t_loc] = f2bf(v1);
        tt[o_loc + 2][t_loc] = f2bf(v2);
        tt[o_loc + 3][t_loc] = f2bf(v3);
      }
    }
  }
  __syncthreads();
  int tid = threadIdx.x;
  if (type < 2) {
    unsigned short* dst = (type == 0) ? qT : kT;
    int obase = y * 64 - type * 256;
    int t_loc = tid >> 2;
    int tg = blockIdx.x * 64 + t_loc;
#pragma unroll
    for (int half = 0; half < 2; ++half) {
      int o_loc = half * 32 + (tid & 3) * 8;
      int o2 = obase + o_loc;
      int hh = o2 >> 5, d = o2 & 31;
      *(uint4*)&dst[(((size_t)b * 8 + hh) * T_ + tg) * HD + d] = *(const uint4*)&tt[t_loc][o_loc];
    }
  } else {
    int obase = y * 64 - 512;
    int o_loc = tid >> 2;
    int o2 = obase + o_loc;
    int hh = o2 >> 5, d = o2 & 31;
    unsigned short* vdst = vW + ((size_t)(b * 8 + hh) * HD + d) * T_ + blockIdx.x * 64;
#pragma unroll
    for (int half = 0; half < 2; ++half) {
      int t_loc = half * 32 + (tid & 3) * 8;
      *(uint4*)&vdst[t_loc] = *(const uint4*)&tt[o_loc][t_loc];
    }
  }
}

// ---------------- flash attention: R8 structure, s-dimension split in 2 (2x waves) ----------
// Each block handles 18 of 36 s-tiles (part = blockIdx.y>>3) and writes UNNORMALIZED bf16
// partial O + partial l. Shift-free softmax makes partial sums exactly combinable.
__global__ __launch_bounds__(128) void attn(const unsigned short* qT, const unsigned short* kT,
                                            const unsigned short* vW, unsigned short* oP0,
                                            unsigned short* oP1, float* lP) {
  int b = blockIdx.z, yy = blockIdx.y, qt = blockIdx.x;
  int h = yy & 7, part = yy >> 3;
  int tid = threadIdx.x, lane = tid & 63, w = tid >> 6;  // w in {0,1}
  int r16 = lane & 15, g4 = lane >> 4;
  __shared__ short Ks[2][64 * 40];   // [s][d] padded to 40, double-buffered
  __shared__ short Vs[2][32 * 72];   // [d][s] padded to 72, double-buffered
  const unsigned short* qB = qT + ((size_t)b * 8 + h) * T_ * HD;
  const unsigned short* kB = kT + ((size_t)b * 8 + h) * T_ * HD;
  const unsigned short* vB = vW + ((size_t)b * 8 + h) * HD * T_;
  int qbase = qt * 64 + w * 32;      // wave owns q-rows [qbase, qbase+32)
  bf16x8 qfA = *(const bf16x8*)(qB + (qbase + r16) * HD + g4 * 8);
  bf16x8 qfB = *(const bf16x8*)(qB + (qbase + 16 + r16) * HD + g4 * 8);
  float lA = 0.f, lB = 0.f;
  f32x4 accA0 = {}, accA1 = {}, accB0 = {}, accB1 = {};
  int t0 = part * 18;

  // cooperative staging: 128 threads, 4x b128 each
  int krow = tid >> 2, kcol = (tid & 3) * 8;   // K rows krow, krow+32
  int vrow = tid >> 3, vcol = (tid & 7) * 8;   // V rows vrow, vrow+16
  const unsigned short* kSrc = kB + (size_t)krow * HD + kcol;
  const unsigned short* vSrc = vB + (size_t)vrow * T_ + vcol;
  int4 rgK0, rgK1, rgV0, rgV1;

  union PU { unsigned u[4]; bf16x8 v; };
  union VU { int2 d2[2]; bf16x8 v; };

#define LOADT(t_) {                                                               \
    const unsigned short* k_ = kSrc + (t_) * 64 * HD;                             \
    rgK0 = *(const int4*)k_;                                                      \
    rgK1 = *(const int4*)(k_ + 32 * HD);                                          \
    const unsigned short* v_ = vSrc + (t_) * 64;                                  \
    rgV0 = *(const int4*)v_;                                                      \
    rgV1 = *(const int4*)(v_ + (size_t)16 * T_);                                  \
  }

#define STORET(bi) {                                                              \
    short* kD = &Ks[bi][krow * 40 + kcol];                                        \
    *(int4*)kD = rgK0;                                                            \
    *(int4*)(kD + 32 * 40) = rgK1;                                                \
    short* vD = &Vs[bi][vrow * 72 + vcol];                                        \
    *(int4*)vD = rgV0;                                                            \
    *(int4*)(vD + 16 * 72) = rgV1;                                                \
  }

// QK -> exp -> pack (lane-local) -> PV through registers. kappa(g4,j) = 4g4+(j&3)+16(j>>2).
#define SUBTILE(qf, lsum, acc0, acc1) {                                           \
    f32x4 z = {};                                                                 \
    f32x4 s0 = __builtin_amdgcn_mfma_f32_16x16x32_bf16(kf0, qf, z, 0, 0, 0);      \
    f32x4 s1 = __builtin_amdgcn_mfma_f32_16x16x32_bf16(kf1, qf, z, 0, 0, 0);      \
    f32x4 s2 = __builtin_amdgcn_mfma_f32_16x16x32_bf16(kf2, qf, z, 0, 0, 0);      \
    f32x4 s3 = __builtin_amdgcn_mfma_f32_16x16x32_bf16(kf3, qf, z, 0, 0, 0);      \
    float p0 = fexp2(s0[0]), p1 = fexp2(s0[1]), p2 = fexp2(s0[2]), p3 = fexp2(s0[3]); \
    float p4 = fexp2(s1[0]), p5 = fexp2(s1[1]), p6 = fexp2(s1[2]), p7 = fexp2(s1[3]); \
    float p8 = fexp2(s2[0]), p9 = fexp2(s2[1]), pa = fexp2(s2[2]), pb = fexp2(s2[3]); \
    float pc = fexp2(s3[0]), pd = fexp2(s3[1]), pe = fexp2(s3[2]), pf = fexp2(s3[3]); \
    float ps = ((p0 + p1) + (p2 + p3)) + ((p4 + p5) + (p6 + p7)) +                \
               ((p8 + p9) + (pa + pb)) + ((pc + pd) + (pe + pf));                 \
    PU w0, w1;                                                                    \
    w0.u[0] = cvtpk(p0, p1); w0.u[1] = cvtpk(p2, p3);                             \
    w0.u[2] = cvtpk(p4, p5); w0.u[3] = cvtpk(p6, p7);                             \
    w1.u[0] = cvtpk(p8, p9); w1.u[1] = cvtpk(pa, pb);                             \
    w1.u[2] = cvtpk(pc, pd); w1.u[3] = cvtpk(pe, pf);                             \
    ps += __shfl_xor(ps, 16);                                                     \
    ps += __shfl_xor(ps, 32);                                                     \
    lsum += ps;                                                                   \
    acc0 = __builtin_amdgcn_mfma_f32_16x16x32_bf16(vf00.v, w0.v, acc0, 0, 0, 0);  \
    acc1 = __builtin_amdgcn_mfma_f32_16x16x32_bf16(vf01.v, w0.v, acc1, 0, 0, 0);  \
    acc0 = __builtin_amdgcn_mfma_f32_16x16x32_bf16(vf10.v, w1.v, acc0, 0, 0, 0);  \
    acc1 = __builtin_amdgcn_mfma_f32_16x16x32_bf16(vf11.v, w1.v, acc1, 0, 0, 0);  \
  }

  // prologue: tile t0 -> LDS buf0, tile t0+1 -> regs
  LOADT(t0)
  STORET(0)
  LOADT(t0 + 1)
  __syncthreads();

  for (int t = 0; t < 18; ++t) {
    int bi = t & 1;
    if (t < 17) STORET(bi ^ 1)          // tile t+1: regs -> other buffer
    if (t < 16) LOADT(t0 + t + 2)       // tile t+2: global -> regs

    const short* Kc = &Ks[bi][0];
    const short* Vc = &Vs[bi][0];
    bf16x8 kf0 = *(const bf16x8*)&Kc[(r16) * 40 + g4 * 8];
    bf16x8 kf1 = *(const bf16x8*)&Kc[(16 + r16) * 40 + g4 * 8];
    bf16x8 kf2 = *(const bf16x8*)&Kc[(32 + r16) * 40 + g4 * 8];
    bf16x8 kf3 = *(const bf16x8*)&Kc[(48 + r16) * 40 + g4 * 8];
    VU vf00, vf01, vf10, vf11;
    {
      const short* vr0 = Vc + r16 * 72;
      const short* vr1 = Vc + (16 + r16) * 72;
      vf00.d2[0] = *(const int2*)(vr0 + 4 * g4);
      vf00.d2[1] = *(const int2*)(vr0 + 16 + 4 * g4);
      vf01.d2[0] = *(const int2*)(vr1 + 4 * g4);
      vf01.d2[1] = *(const int2*)(vr1 + 16 + 4 * g4);
      vf10.d2[0] = *(const int2*)(vr0 + 32 + 4 * g4);
      vf10.d2[1] = *(const int2*)(vr0 + 48 + 4 * g4);
      vf11.d2[0] = *(const int2*)(vr1 + 32 + 4 * g4);
      vf11.d2[1] = *(const int2*)(vr1 + 48 + 4 * g4);
    }

    SUBTILE(qfA, lA, accA0, accA1)
    SUBTILE(qfB, lB, accB0, accB1)

    __syncthreads();                    // tile t consumed; tile t+1 stores visible
  }

  // epilogue: UNNORMALIZED partial O (bf16) + partial l
  unsigned short* dst = part ? oP1 : oP0;
  unsigned short* oA = dst + ((size_t)b * T_ + qbase + r16) * C_ + h * HD + 4 * g4;
  unsigned short* oB = dst + ((size_t)b * T_ + qbase + 16 + r16) * C_ + h * HD + 4 * g4;
  {
    u32x2 wA0 = {cvtpk(accA0[0], accA0[1]), cvtpk(accA0[2], accA0[3])};
    u32x2 wA1 = {cvtpk(accA1[0], accA1[1]), cvtpk(accA1[2], accA1[3])};
    u32x2 wB0 = {cvtpk(accB0[0], accB0[1]), cvtpk(accB0[2], accB0[3])};
    u32x2 wB1 = {cvtpk(accB1[0], accB1[1]), cvtpk(accB1[2], accB1[3])};
    *(u32x2*)oA = wA0;
    *(u32x2*)(oA + 16) = wA1;
    *(u32x2*)oB = wB0;
    *(u32x2*)(oB + 16) = wB1;
  }
  if (g4 == 0) {
    size_t lb = ((size_t)part * 32 + b * 8 + h) * T_;
    lP[lb + qbase + r16] = lA;
    lP[lb + qbase + 16 + r16] = lB;
  }
#undef LOADT
#undef STORET
#undef SUBTILE
}

// ---------------- combine partials: aT = (o0 + o1) / (l0 + l1) ----------------
__global__ __launch_bounds__(256) void combine(const unsigned short* o0, const unsigned short* o1,
                                               const float* lP, unsigned short* out) {
  unsigned i8 = blockIdx.x * 256 + threadIdx.x;   // chunk of 8 channels
  size_t i = (size_t)i8 * 8;
  unsigned b = i8 / 73728u;                       // T*C/8 = 73728 chunks per batch
  unsigned rem = i8 - b * 73728u;
  unsigned t = rem >> 5;                          // C/8 = 32 chunks per t
  unsigned c8 = (rem & 31u) * 8u;
  unsigned h = c8 >> 5;
  float l0 = lP[((size_t)b * 8 + h) * T_ + t];
  float l1 = lP[((size_t)(32 + b * 8 + h)) * T_ + t];
  float inv = 1.f / (l0 + l1);
  uint4 A = *(const uint4*)&o0[i];
  uint4 Bv = *(const uint4*)&o1[i];
  unsigned out4[4];
  const unsigned* Au = (const unsigned*)&A;
  const unsigned* Bu = (const unsigned*)&Bv;
#pragma unroll
  for (int k = 0; k < 4; ++k) {
    unsigned a = Au[k], bb = Bu[k];
    float a0 = __uint_as_float((a & 0xFFFFu) << 16);
    float a1 = __uint_as_float(a & 0xFFFF0000u);
    float b0 = __uint_as_float((bb & 0xFFFFu) << 16);
    float b1 = __uint_as_float(bb & 0xFFFF0000u);
    out4[k] = cvtpk((a0 + b0) * inv, (a1 + b1) * inv);
  }
  *(uint4*)&out[i] = *(const uint4*)out4;
}

// ---------------- proj GEMM + bias + residual ----------------
__global__ __launch_bounds__(256) void proj_gemm(const unsigned short* W, const unsigned short* aT,
                                                 const float* bias, const float* x, float* out) {
  int b = blockIdx.z;
  int lane = threadIdx.x & 63, w = threadIdx.x >> 6;
  int r16 = lane & 15, g4 = lane >> 4;
  int m0 = blockIdx.y * 64 + (w >> 1) * 32;
  int n0 = blockIdx.x * 64 + (w & 1) * 32;
  const bf16x8* Wv = (const bf16x8*)W;
  const bf16x8* Av = (const bf16x8*)(aT + (size_t)b * T_ * C_);
  f32x4 acc[2][2] = {};
  for (int k0 = 0; k0 < C_; k0 += 32) {
    bf16x8 af[2], bfr[2];
    for (int mi = 0; mi < 2; ++mi)
      af[mi] = Wv[((m0 + mi * 16 + r16) * C_ + k0 + g4 * 8) >> 3];
    for (int ni = 0; ni < 2; ++ni)
      bfr[ni] = Av[((n0 + ni * 16 + r16) * C_ + k0 + g4 * 8) >> 3];
    for (int mi = 0; mi < 2; ++mi)
      for (int ni = 0; ni < 2; ++ni)
        acc[mi][ni] = __builtin_amdgcn_mfma_f32_16x16x32_bf16(af[mi], bfr[ni], acc[mi][ni], 0, 0, 0);
  }
  for (int mi = 0; mi < 2; ++mi)
    for (int ni = 0; ni < 2; ++ni) {
      int t = n0 + ni * 16 + r16;
      for (int r = 0; r < 4; ++r) {
        int o = m0 + mi * 16 + g4 * 4 + r;
        size_t idx = ((size_t)b * C_ + o) * T_ + t;
        out[idx] = x[idx] + acc[mi][ni][r] + bias[o];
      }
    }
}

extern "C" void kernel_launch(void* const* d_in, const int* in_sizes, int n_in,
                              void* d_out, int out_size, void* d_ws, size_t ws_size,
                              hipStream_t stream) {
  const float* x  = (const float*)d_in[0];
  const float* gw = (const float*)d_in[1];
  const float* gb = (const float*)d_in[2];
  const float* wq = (const float*)d_in[3];
  const float* bq = (const float*)d_in[4];
  const float* wp = (const float*)d_in[5];
  const float* bp = (const float*)d_in[6];

  char* ws = (char*)d_ws;
  float* ws1 = (float*)ws;                       // 256*2 f32
  unsigned short* wqb = (unsigned short*)(ws + 4096);
  unsigned short* wpb = wqb + 3 * C_ * C_;
  unsigned short* nT  = wpb + C_ * C_;
  const size_t NE = (size_t)B_ * T_ * C_;        // 2359296
  unsigned short* qT = nT + NE;
  unsigned short* kT = qT + NE;
  unsigned short* vW = kT + NE;
  unsigned short* aT = vW + NE;
  float* lP = (float*)(aT + NE);                 // 2*32*2304 f32 = 590 KB

  prep<<<1280, 256, 0, stream>>>(wq, wp, x, wqb, wpb, ws1);
  gn_norm<<<dim3(72, 4), 256, 0, stream>>>(x, ws1, gw, gb, nT);
  qkv_gemm<<<dim3(36, 12, 4), 256, 0, stream>>>(wqb, nT, bq, qT, kT, vW);
  // part0 partials -> aT region, part1 partials -> nT region (dead after qkv)
  attn<<<dim3(36, 16, 4), 128, 0, stream>>>(qT, kT, vW, aT, nT, lP);
  combine<<<1152, 256, 0, stream>>>(aT, nT, lP, aT);
  proj_gemm<<<dim3(36, 4, 4), 256, 0, stream>>>(wpb, aT, bp, x, (float*)d_out);
}

// Round 16
// 104.546 us; speedup vs baseline: 1.7319x; 1.0316x over previous
//
#include <hip/hip_runtime.h>

#define B_ 4
#define C_ 256
#define T_ 2304
#define HD 32
#define GSZ (32 * T_)                 // elems per groupnorm group = 73728
#define SCL2E (0.17677669529663687f * 1.44269504088896f)  // (1/sqrt(32)) * log2(e)

typedef short bf16x8 __attribute__((ext_vector_type(8)));
typedef float f32x4 __attribute__((ext_vector_type(4)));
typedef unsigned int u32x2 __attribute__((ext_vector_type(2)));

__device__ inline unsigned short f2bf(float f) {
  unsigned int u = __float_as_uint(f);
  return (unsigned short)((u + 0x7FFFu + ((u >> 16) & 1u)) >> 16);
}

__device__ inline float fexp2(float x) {
  float r;
  asm("v_exp_f32 %0, %1" : "=v"(r) : "v"(x));
  return r;
}

__device__ inline unsigned cvtpk(float lo, float hi) {
  unsigned r;
  asm("v_cvt_pk_bf16_f32 %0, %1, %2" : "=v"(r) : "v"(lo), "v"(hi));
  return r;
}

// ---------------- weights -> bf16  +  groupnorm partial stats (merged) ----------------
__global__ void prep(const float* wq, const float* wp, const float* x,
                     unsigned short* oq, unsigned short* op, float* ws1) {
  if (blockIdx.x < 1024) {
    int i = blockIdx.x * 256 + threadIdx.x;
    const int n1 = 3 * C_ * C_;
    if (i < n1) oq[i] = f2bf(wq[i]);
    else        op[i - n1] = f2bf(wp[i - n1]);
    return;
  }
  int bid = blockIdx.x - 1024;
  int bg = bid >> 3, sl = bid & 7;
  const float4* p = (const float4*)(x + (size_t)bg * GSZ + sl * (GSZ / 8));
  float s = 0.f, q = 0.f;
  for (int it = 0; it < 9; ++it) {
    float4 v = p[it * 256 + threadIdx.x];
    s += v.x + v.y + v.z + v.w;
    q += v.x * v.x + v.y * v.y + v.z * v.z + v.w * v.w;
  }
  for (int off = 32; off; off >>= 1) {
    s += __shfl_down(s, off);
    q += __shfl_down(q, off);
  }
  __shared__ float red[8];
  int w = threadIdx.x >> 6;
  if ((threadIdx.x & 63) == 0) { red[w * 2] = s; red[w * 2 + 1] = q; }
  __syncthreads();
  if (threadIdx.x == 0) {
    float S = red[0] + red[2] + red[4] + red[6];
    float Q = red[1] + red[3] + red[5] + red[7];
    ws1[bid * 2] = S;
    ws1[bid * 2 + 1] = Q;
  }
}

// ---------------- groupnorm: finalize stats (inline) + normalize + transpose to nT[B][T][C] --
__global__ void gn_norm(const float* x, const float* ws1, const float* gamma,
                        const float* beta, unsigned short* nT) {
  int b = blockIdx.y, t0 = blockIdx.x * 32;
  __shared__ unsigned short tile[32 * 264];
  __shared__ float stl[16];
  int tid = threadIdx.x;
  if (tid < 8) {
    float S = 0.f, Q = 0.f;
    for (int sl = 0; sl < 8; ++sl) {
      S += ws1[((b * 8 + tid) * 8 + sl) * 2];
      Q += ws1[((b * 8 + tid) * 8 + sl) * 2 + 1];
    }
    float mean = S / (float)GSZ;
    float var = Q / (float)GSZ - mean * mean;
    stl[tid * 2] = mean;
    stl[tid * 2 + 1] = rsqrtf(var + 1e-5f);
  }
  __syncthreads();
#pragma unroll
  for (int it = 0; it < 8; ++it) {
    int qd = it * 256 + tid;
    int c = qd >> 3, tq = qd & 7;
    float4 v = *(const float4*)&x[((size_t)b * C_ + c) * T_ + t0 + tq * 4];
    int g = c >> 5;
    float mean = stl[g * 2], rstd = stl[g * 2 + 1];
    float sc = rstd * gamma[c];
    float sh = beta[c] - mean * sc;
    tile[(tq * 4 + 0) * 264 + c] = f2bf(v.x * sc + sh);
    tile[(tq * 4 + 1) * 264 + c] = f2bf(v.y * sc + sh);
    tile[(tq * 4 + 2) * 264 + c] = f2bf(v.z * sc + sh);
    tile[(tq * 4 + 3) * 264 + c] = f2bf(v.w * sc + sh);
  }
  __syncthreads();
#pragma unroll
  for (int it = 0; it < 4; ++it) {
    int qd = it * 256 + tid;
    int tt = qd >> 5, c8 = (qd & 31) * 8;
    *(uint4*)&nT[((size_t)b * T_ + t0 + tt) * C_ + c8] = *(const uint4*)&tile[tt * 264 + c8];
  }
}

// ---------------- QKV GEMM: [768,256] x nT -> qT/kT [b,h,t,d], v [b,h,d,t] ----------------
__global__ __launch_bounds__(256) void qkv_gemm(const unsigned short* W, const unsigned short* nT,
                                                const float* bias, unsigned short* qT,
                                                unsigned short* kT, unsigned short* vW) {
  __shared__ unsigned short tt[64][72];
  int b = blockIdx.z;
  int lane = threadIdx.x & 63, w = threadIdx.x >> 6;
  int r16 = lane & 15, g4 = lane >> 4;
  int y = blockIdx.y;
  int type = y >> 2;                    // 0=q 1=k 2=v
  int m0 = y * 64 + (w >> 1) * 32;
  int n0 = blockIdx.x * 64 + (w & 1) * 32;
  const bf16x8* Wv = (const bf16x8*)W;
  const bf16x8* Nv = (const bf16x8*)(nT + (size_t)b * T_ * C_);
  f32x4 acc[2][2] = {};
  for (int k0 = 0; k0 < C_; k0 += 32) {
    bf16x8 af[2], bfr[2];
    for (int mi = 0; mi < 2; ++mi)
      af[mi] = Wv[((m0 + mi * 16 + r16) * C_ + k0 + g4 * 8) >> 3];
    for (int ni = 0; ni < 2; ++ni)
      bfr[ni] = Nv[((n0 + ni * 16 + r16) * C_ + k0 + g4 * 8) >> 3];
    for (int mi = 0; mi < 2; ++mi)
      for (int ni = 0; ni < 2; ++ni)
        acc[mi][ni] = __builtin_amdgcn_mfma_f32_16x16x32_bf16(af[mi], bfr[ni], acc[mi][ni], 0, 0, 0);
  }
#pragma unroll
  for (int mi = 0; mi < 2; ++mi) {
#pragma unroll
    for (int ni = 0; ni < 2; ++ni) {
      int t_loc = (w & 1) * 32 + ni * 16 + r16;
      int o_loc = (w >> 1) * 32 + mi * 16 + g4 * 4;
      int o = y * 64 + o_loc;
      float v0 = acc[mi][ni][0] + bias[o + 0];
      float v1 = acc[mi][ni][1] + bias[o + 1];
      float v2 = acc[mi][ni][2] + bias[o + 2];
      float v3 = acc[mi][ni][3] + bias[o + 3];
      if (type == 0) { v0 *= SCL2E; v1 *= SCL2E; v2 *= SCL2E; v3 *= SCL2E; }
      if (type < 2) {
        u32x2 pw = {cvtpk(v0, v1), cvtpk(v2, v3)};
        *(u32x2*)&tt[t_loc][o_loc] = pw;          // [t][o]
      } else {
        tt[o_loc + 0][t_loc] = f2bf(v0);          // [o][t]
        tt[o_loc + 1][t_loc] = f2bf(v1);
        tt[o_loc + 2][t_loc] = f2bf(v2);
        tt[o_loc + 3][t_loc] = f2bf(v3);
      }
    }
  }
  __syncthreads();
  int tid = threadIdx.x;
  if (type < 2) {
    unsigned short* dst = (type == 0) ? qT : kT;
    int obase = y * 64 - type * 256;
    int t_loc = tid >> 2;
    int tg = blockIdx.x * 64 + t_loc;
#pragma unroll
    for (int half = 0; half < 2; ++half) {
      int o_loc = half * 32 + (tid & 3) * 8;
      int o2 = obase + o_loc;
      int hh = o2 >> 5, d = o2 & 31;
      *(uint4*)&dst[(((size_t)b * 8 + hh) * T_ + tg) * HD + d] = *(const uint4*)&tt[t_loc][o_loc];
    }
  } else {
    int obase = y * 64 - 512;
    int o_loc = tid >> 2;
    int o2 = obase + o_loc;
    int hh = o2 >> 5, d = o2 & 31;
    unsigned short* vdst = vW + ((size_t)(b * 8 + hh) * HD + d) * T_ + blockIdx.x * 64;
#pragma unroll
    for (int half = 0; half < 2; ++half) {
      int t_loc = half * 32 + (tid & 3) * 8;
      *(uint4*)&vdst[t_loc] = *(const uint4*)&tt[o_loc][t_loc];
    }
  }
}

// ---------------- flash attention: 4 waves = 2 s-parts x 2 q-subwaves, in-block combine -----
// Waves {0,1}: s-tiles 0-17 on tileset 0; waves {2,3}: s-tiles 18-35 on tileset 1.
// After the loop, part-1 waves drop f32 acc+l into dead tileset-1 LDS; part-0 waves add,
// normalize, write final bf16 O. No global partials, no combine kernel.
__global__ __launch_bounds__(256) void attn(const unsigned short* qT, const unsigned short* kT,
                                            const unsigned short* vW, unsigned short* aT) {
  int b = blockIdx.z, h = blockIdx.y, qt = blockIdx.x;
  int tid = threadIdx.x, lane = tid & 63, w = tid >> 6;  // w in {0..3}
  int part = w >> 1, wsub = w & 1;
  int r16 = lane & 15, g4 = lane >> 4;
  __shared__ short Ks[2][2][64 * 40];   // [part][buf][s][d] padded to 40
  __shared__ short Vs[2][2][32 * 72];   // [part][buf][d][s] padded to 72
  const unsigned short* qB = qT + ((size_t)b * 8 + h) * T_ * HD;
  const unsigned short* kB = kT + ((size_t)b * 8 + h) * T_ * HD;
  const unsigned short* vB = vW + ((size_t)b * 8 + h) * HD * T_;
  int qbase = qt * 64 + wsub * 32;      // wave owns q-rows [qbase, qbase+32)
  bf16x8 qfA = *(const bf16x8*)(qB + (qbase + r16) * HD + g4 * 8);
  bf16x8 qfB = *(const bf16x8*)(qB + (qbase + 16 + r16) * HD + g4 * 8);
  float lA = 0.f, lB = 0.f;
  f32x4 accA0 = {}, accA1 = {}, accB0 = {}, accB1 = {};
  int t0 = part * 18;

  // staging: each 2-wave part (128 threads) stages its own tileset, 4x b128 per thread
  int tp = tid & 127;
  int krow = tp >> 2, kcol = (tid & 3) * 8;   // K rows krow, krow+32
  int vrow = tp >> 3, vcol = (tid & 7) * 8;   // V rows vrow, vrow+16
  const unsigned short* kSrc = kB + (size_t)krow * HD + kcol;
  const unsigned short* vSrc = vB + (size_t)vrow * T_ + vcol;
  int4 rgK0, rgK1, rgV0, rgV1;

  union PU { unsigned u[4]; bf16x8 v; };
  union VU { int2 d2[2]; bf16x8 v; };

#define LOADT(t_) {                                                               \
    const unsigned short* k_ = kSrc + (t_) * 64 * HD;                             \
    rgK0 = *(const int4*)k_;                                                      \
    rgK1 = *(const int4*)(k_ + 32 * HD);                                          \
    const unsigned short* v_ = vSrc + (t_) * 64;                                  \
    rgV0 = *(const int4*)v_;                                                      \
    rgV1 = *(const int4*)(v_ + (size_t)16 * T_);                                  \
  }

#define STORET(bi) {                                                              \
    short* kD = &Ks[part][bi][krow * 40 + kcol];                                  \
    *(int4*)kD = rgK0;                                                            \
    *(int4*)(kD + 32 * 40) = rgK1;                                                \
    short* vD = &Vs[part][bi][vrow * 72 + vcol];                                  \
    *(int4*)vD = rgV0;                                                            \
    *(int4*)(vD + 16 * 72) = rgV1;                                                \
  }

// QK -> exp -> pack (lane-local) -> PV through registers. kappa(g4,j) = 4g4+(j&3)+16(j>>2).
#define SUBTILE(qf, lsum, acc0, acc1) {                                           \
    f32x4 z = {};                                                                 \
    f32x4 s0 = __builtin_amdgcn_mfma_f32_16x16x32_bf16(kf0, qf, z, 0, 0, 0);      \
    f32x4 s1 = __builtin_amdgcn_mfma_f32_16x16x32_bf16(kf1, qf, z, 0, 0, 0);      \
    f32x4 s2 = __builtin_amdgcn_mfma_f32_16x16x32_bf16(kf2, qf, z, 0, 0, 0);      \
    f32x4 s3 = __builtin_amdgcn_mfma_f32_16x16x32_bf16(kf3, qf, z, 0, 0, 0);      \
    float p0 = fexp2(s0[0]), p1 = fexp2(s0[1]), p2 = fexp2(s0[2]), p3 = fexp2(s0[3]); \
    float p4 = fexp2(s1[0]), p5 = fexp2(s1[1]), p6 = fexp2(s1[2]), p7 = fexp2(s1[3]); \
    float p8 = fexp2(s2[0]), p9 = fexp2(s2[1]), pa = fexp2(s2[2]), pb = fexp2(s2[3]); \
    float pc = fexp2(s3[0]), pd = fexp2(s3[1]), pe = fexp2(s3[2]), pf = fexp2(s3[3]); \
    float ps = ((p0 + p1) + (p2 + p3)) + ((p4 + p5) + (p6 + p7)) +                \
               ((p8 + p9) + (pa + pb)) + ((pc + pd) + (pe + pf));                 \
    PU w0, w1;                                                                    \
    w0.u[0] = cvtpk(p0, p1); w0.u[1] = cvtpk(p2, p3);                             \
    w0.u[2] = cvtpk(p4, p5); w0.u[3] = cvtpk(p6, p7);                             \
    w1.u[0] = cvtpk(p8, p9); w1.u[1] = cvtpk(pa, pb);                             \
    w1.u[2] = cvtpk(pc, pd); w1.u[3] = cvtpk(pe, pf);                             \
    ps += __shfl_xor(ps, 16);                                                     \
    ps += __shfl_xor(ps, 32);                                                     \
    lsum += ps;                                                                   \
    acc0 = __builtin_amdgcn_mfma_f32_16x16x32_bf16(vf00.v, w0.v, acc0, 0, 0, 0);  \
    acc1 = __builtin_amdgcn_mfma_f32_16x16x32_bf16(vf01.v, w0.v, acc1, 0, 0, 0);  \
    acc0 = __builtin_amdgcn_mfma_f32_16x16x32_bf16(vf10.v, w1.v, acc0, 0, 0, 0);  \
    acc1 = __builtin_amdgcn_mfma_f32_16x16x32_bf16(vf11.v, w1.v, acc1, 0, 0, 0);  \
  }

  // prologue: tile t0 -> buf0, tile t0+1 -> regs
  LOADT(t0)
  STORET(0)
  LOADT(t0 + 1)
  __syncthreads();

  for (int t = 0; t < 18; ++t) {
    int bi = t & 1;
    if (t < 17) STORET(bi ^ 1)          // tile t+1: regs -> other buffer
    if (t < 16) LOADT(t0 + t + 2)       // tile t+2: global -> regs

    const short* Kc = &Ks[part][bi][0];
    const short* Vc = &Vs[part][bi][0];
    bf16x8 kf0 = *(const bf16x8*)&Kc[(r16) * 40 + g4 * 8];
    bf16x8 kf1 = *(const bf16x8*)&Kc[(16 + r16) * 40 + g4 * 8];
    bf16x8 kf2 = *(const bf16x8*)&Kc[(32 + r16) * 40 + g4 * 8];
    bf16x8 kf3 = *(const bf16x8*)&Kc[(48 + r16) * 40 + g4 * 8];
    VU vf00, vf01, vf10, vf11;
    {
      const short* vr0 = Vc + r16 * 72;
      const short* vr1 = Vc + (16 + r16) * 72;
      vf00.d2[0] = *(const int2*)(vr0 + 4 * g4);
      vf00.d2[1] = *(const int2*)(vr0 + 16 + 4 * g4);
      vf01.d2[0] = *(const int2*)(vr1 + 4 * g4);
      vf01.d2[1] = *(const int2*)(vr1 + 16 + 4 * g4);
      vf10.d2[0] = *(const int2*)(vr0 + 32 + 4 * g4);
      vf10.d2[1] = *(const int2*)(vr0 + 48 + 4 * g4);
      vf11.d2[0] = *(const int2*)(vr1 + 32 + 4 * g4);
      vf11.d2[1] = *(const int2*)(vr1 + 48 + 4 * g4);
    }

    SUBTILE(qfA, lA, accA0, accA1)
    SUBTILE(qfB, lB, accB0, accB1)

    __syncthreads();                    // tile t consumed; tile t+1 stores visible
  }

  // ---- in-block combine: part1 -> LDS (dead tileset-1 space), part0 adds + writes ----
  float* ex = (float*)&Ks[1][0][0];     // 2 waves x 64 lanes x 16 f32 = 8 KB
  float* lex = ex + 2048;               // 2 waves x 64 lanes x 2 f32
  if (part == 1) {
    f32x4* dst = (f32x4*)&ex[(wsub * 64 + lane) * 16];
    dst[0] = accA0; dst[1] = accA1; dst[2] = accB0; dst[3] = accB1;
    lex[(wsub * 64 + lane) * 2] = lA;
    lex[(wsub * 64 + lane) * 2 + 1] = lB;
  }
  __syncthreads();
  if (part == 0) {
    const f32x4* src = (const f32x4*)&ex[(wsub * 64 + lane) * 16];
    accA0 += src[0]; accA1 += src[1]; accB0 += src[2]; accB1 += src[3];
    lA += lex[(wsub * 64 + lane) * 2];
    lB += lex[(wsub * 64 + lane) * 2 + 1];
    float invA = 1.f / lA;
    float invB = 1.f / lB;
    unsigned short* oA = aT + ((size_t)b * T_ + qbase + r16) * C_ + h * HD + 4 * g4;
    unsigned short* oB = aT + ((size_t)b * T_ + qbase + 16 + r16) * C_ + h * HD + 4 * g4;
    u32x2 wA0 = {cvtpk(accA0[0] * invA, accA0[1] * invA), cvtpk(accA0[2] * invA, accA0[3] * invA)};
    u32x2 wA1 = {cvtpk(accA1[0] * invA, accA1[1] * invA), cvtpk(accA1[2] * invA, accA1[3] * invA)};
    u32x2 wB0 = {cvtpk(accB0[0] * invB, accB0[1] * invB), cvtpk(accB0[2] * invB, accB0[3] * invB)};
    u32x2 wB1 = {cvtpk(accB1[0] * invB, accB1[1] * invB), cvtpk(accB1[2] * invB, accB1[3] * invB)};
    *(u32x2*)oA = wA0;
    *(u32x2*)(oA + 16) = wA1;
    *(u32x2*)oB = wB0;
    *(u32x2*)(oB + 16) = wB1;
  }
#undef LOADT
#undef STORET
#undef SUBTILE
}

// ---------------- proj GEMM + bias + residual ----------------
__global__ __launch_bounds__(256) void proj_gemm(const unsigned short* W, const unsigned short* aT,
                                                 const float* bias, const float* x, float* out) {
  int b = blockIdx.z;
  int lane = threadIdx.x & 63, w = threadIdx.x >> 6;
  int r16 = lane & 15, g4 = lane >> 4;
  int m0 = blockIdx.y * 64 + (w >> 1) * 32;
  int n0 = blockIdx.x * 64 + (w & 1) * 32;
  const bf16x8* Wv = (const bf16x8*)W;
  const bf16x8* Av = (const bf16x8*)(aT + (size_t)b * T_ * C_);
  f32x4 acc[2][2] = {};
  for (int k0 = 0; k0 < C_; k0 += 32) {
    bf16x8 af[2], bfr[2];
    for (int mi = 0; mi < 2; ++mi)
      af[mi] = Wv[((m0 + mi * 16 + r16) * C_ + k0 + g4 * 8) >> 3];
    for (int ni = 0; ni < 2; ++ni)
      bfr[ni] = Av[((n0 + ni * 16 + r16) * C_ + k0 + g4 * 8) >> 3];
    for (int mi = 0; mi < 2; ++mi)
      for (int ni = 0; ni < 2; ++ni)
        acc[mi][ni] = __builtin_amdgcn_mfma_f32_16x16x32_bf16(af[mi], bfr[ni], acc[mi][ni], 0, 0, 0);
  }
  for (int mi = 0; mi < 2; ++mi)
    for (int ni = 0; ni < 2; ++ni) {
      int t = n0 + ni * 16 + r16;
      for (int r = 0; r < 4; ++r) {
        int o = m0 + mi * 16 + g4 * 4 + r;
        size_t idx = ((size_t)b * C_ + o) * T_ + t;
        out[idx] = x[idx] + acc[mi][ni][r] + bias[o];
      }
    }
}

extern "C" void kernel_launch(void* const* d_in, const int* in_sizes, int n_in,
                              void* d_out, int out_size, void* d_ws, size_t ws_size,
                              hipStream_t stream) {
  const float* x  = (const float*)d_in[0];
  const float* gw = (const float*)d_in[1];
  const float* gb = (const float*)d_in[2];
  const float* wq = (const float*)d_in[3];
  const float* bq = (const float*)d_in[4];
  const float* wp = (const float*)d_in[5];
  const float* bp = (const float*)d_in[6];

  char* ws = (char*)d_ws;
  float* ws1 = (float*)ws;                       // 256*2 f32
  unsigned short* wqb = (unsigned short*)(ws + 4096);
  unsigned short* wpb = wqb + 3 * C_ * C_;
  unsigned short* nT  = wpb + C_ * C_;
  const size_t NE = (size_t)B_ * T_ * C_;        // 2359296
  unsigned short* qT = nT + NE;
  unsigned short* kT = qT + NE;
  unsigned short* vW = kT + NE;
  unsigned short* aT = vW + NE;

  prep<<<1280, 256, 0, stream>>>(wq, wp, x, wqb, wpb, ws1);
  gn_norm<<<dim3(72, 4), 256, 0, stream>>>(x, ws1, gw, gb, nT);
  qkv_gemm<<<dim3(36, 12, 4), 256, 0, stream>>>(wqb, nT, bq, qT, kT, vW);
  attn<<<dim3(36, 8, 4), 256, 0, stream>>>(qT, kT, vW, aT);
  proj_gemm<<<dim3(36, 4, 4), 256, 0, stream>>>(wpb, aT, bp, x, (float*)d_out);
}